// Round 17
// baseline (1051.339 us; speedup 1.0000x reference)
//
#include <hip/hip_runtime.h>

// ---------------------------------------------------------------------------
// UltimateTNN: MoE-ish transformer forward on MI355X (gfx950).
// B=8 S=512 H=1024 HF=512 V=32000 L=4 NB=8 K=2, M = B*S = 4096.
// Round 17: gemm_lm -> 128x128 tile, 4 waves, 64 KB LDS = 2 blocks/CU
// (cross-block overlap; round-7 retried with a FITTING register ledger:
// acc[4][4]=64 VGPR < 256 cap). 2-barrier counted schedule, whole-tile units.
// Residual x bf16; layer GEMMs BK=128 (round 15/16 baseline).
// ---------------------------------------------------------------------------

typedef unsigned short u16;
typedef short bf16x8 __attribute__((ext_vector_type(8)));
typedef float f32x4 __attribute__((ext_vector_type(4)));

struct __align__(8) u16x4_t { u16 x, y, z, w; };

#define MTOT 4096
#define HDIM 1024
#define HFF  512
#define VOC  32000
#define NLAYER 4
#define NBLK 8

#define VMW(n) asm volatile("s_waitcnt vmcnt(" #n ")" ::: "memory")
#define BARR() do { asm volatile("" ::: "memory"); __builtin_amdgcn_s_barrier(); asm volatile("" ::: "memory"); } while (0)

__device__ __forceinline__ u16 f2bf(float f) {
  unsigned u = __float_as_uint(f);
  unsigned r = u + 0x7FFFu + ((u >> 16) & 1u);
  return (u16)(r >> 16);
}

__device__ __forceinline__ float b2f(u16 v) {
  return __uint_as_float(((unsigned)v) << 16);
}

__device__ __forceinline__ float sigmoidf_(float z) {
  return 1.0f / (1.0f + expf(-z));
}

__device__ __forceinline__ void gload16(const void* g, void* l) {
  __builtin_amdgcn_global_load_lds(
      (const __attribute__((address_space(1))) void*)g,
      (__attribute__((address_space(3))) void*)l, 16, 0, 0);
}

// ---------------- embed + lm_w transpose (merged, independent) --------------
__global__ void embed_lm_kernel(const int* __restrict__ ids,
                                const float* __restrict__ emb,
                                const float* __restrict__ pos,
                                u16* __restrict__ x,
                                const float* __restrict__ lm_w,
                                u16* __restrict__ lmT) {
  __shared__ float tile[32][33];
  int b = blockIdx.x, tid = threadIdx.x;
  if (b < MTOT) {
    int s = b & 511;
    int id = ids[b];
    float4 e = ((const float4*)(emb + (size_t)id * HDIM))[tid];
    float4 p = ((const float4*)(pos + (size_t)s * HDIM))[tid];
    u16x4_t r;
    r.x = f2bf(e.x + p.x); r.y = f2bf(e.y + p.y);
    r.z = f2bf(e.z + p.z); r.w = f2bf(e.w + p.w);
    ((u16x4_t*)(x + (size_t)b * HDIM))[tid] = r;
    return;
  }
  int c = b - MTOT;                 // 0..31999
  int n0 = (c % 1000) * 32, k0 = (c / 1000) * 32;
  int tx = tid & 31, ty = tid >> 5; // (32,8)
#pragma unroll
  for (int j = 0; j < 4; ++j) {
    int kr = k0 + ty + j * 8;
    tile[ty + j * 8][tx] = lm_w[(size_t)kr * VOC + n0 + tx];
  }
  __syncthreads();
#pragma unroll
  for (int j = 0; j < 4; ++j) {
    int nr = n0 + ty + j * 8;
    lmT[(size_t)nr * HDIM + k0 + tx] = f2bf(tile[tx][ty + j * 8]);
  }
}

// --------------------------- router ----------------------------------------
__global__ void colsum_kernel(const u16* __restrict__ x, float* __restrict__ partial) {
  int j = blockIdx.x;            // 0..63
  int t = threadIdx.x;           // 0..255 (4 elems each)
  float4 s; s.x = 0.f; s.y = 0.f; s.z = 0.f; s.w = 0.f;
  for (int r = 0; r < 8; ++r) {
    u16x4_t a = ((const u16x4_t*)(x + (size_t)(j * 8 + r) * HDIM))[t];
    s.x += b2f(a.x); s.y += b2f(a.y); s.z += b2f(a.z); s.w += b2f(a.w);
  }
  ((float4*)(partial + (size_t)j * HDIM))[t] = s;
}

__global__ void router_finalize(const float* __restrict__ partial,
                                const float* __restrict__ selw,   // [H][NB]
                                const float* __restrict__ selb,   // [NB]
                                const float* __restrict__ tg_l,   // [NB][H]
                                const float* __restrict__ tf,     // [H]
                                int* __restrict__ idx_out,        // [2]
                                float* __restrict__ scale_out) {  // [2][H]
  int t = threadIdx.x;           // 0..1023
  float s = 0.f;
  for (int j = 0; j < 64; ++j) s += partial[(size_t)j * HDIM + t];
  float mean = s * (1.0f / 512.0f);
  __shared__ float sm[HDIM];
  __shared__ float sc[NBLK];
  __shared__ int sidx[2];
  sm[t] = mean;
  __syncthreads();
  int wave = t >> 6, lane = t & 63;
  if (wave < NBLK) {
    float p = 0.f;
    for (int h = lane; h < HDIM; h += 64) p += sm[h] * selw[h * NBLK + wave];
    for (int o = 32; o; o >>= 1) p += __shfl_down(p, o);
    if (lane == 0) sc[wave] = p;
  }
  __syncthreads();
  if (t == 0) {
    float adj[NBLK];
    for (int i = 0; i < NBLK; ++i) {
      float z = sc[i] + selb[i];
      adj[i] = sigmoidf_(z) * 0.7f + 0.15f;   // PRIORITY=0.5 * 0.3
    }
    int i0 = 0;
    for (int i = 1; i < NBLK; ++i) if (adj[i] > adj[i0]) i0 = i;
    int i1 = -1;
    for (int i = 0; i < NBLK; ++i) {
      if (i == i0) continue;
      if (i1 < 0 || adj[i] > adj[i1]) i1 = i;
    }
    idx_out[0] = i0; idx_out[1] = i1;
    sidx[0] = i0; sidx[1] = i1;
  }
  __syncthreads();
  for (int k = 0; k < 2; ++k) {
    int id = sidx[k];
    float z = tg_l[(size_t)id * HDIM + t];
    scale_out[k * HDIM + t] = 1.0f + sigmoidf_(z) * tf[t];
  }
}

// --------- prep: weight transpose (slot k) + LN1 (slot k), one launch ------
__global__ void prep_kernel(const float* __restrict__ aw,
                            const float* __restrict__ f1w,
                            const float* __restrict__ f2w,
                            const int* __restrict__ idx, int slot,
                            u16* __restrict__ wA, u16* __restrict__ w1,
                            u16* __restrict__ w2,
                            const u16* __restrict__ x,
                            const float* __restrict__ g_base,
                            const float* __restrict__ b_base,
                            u16* __restrict__ abf) {
  __shared__ float sh[32 * 33];
  int b = blockIdx.x, tid = threadIdx.x;
  int id = idx[slot];
  if (b < 2048) {
    float (*tile)[33] = (float(*)[33])sh;
    const float* src; u16* dst; int K, N, n0, k0;
    if (b < 1024) {
      K = 1024; N = 1024; src = aw + (size_t)id * 1024 * 1024;
      n0 = (b & 31) * 32; k0 = (b >> 5) * 32; dst = wA;
    } else if (b < 1536) {
      int c = b - 1024; K = 1024; N = 512; src = f1w + (size_t)id * 1024 * 512;
      n0 = (c & 15) * 32; k0 = (c >> 4) * 32; dst = w1;
    } else {
      int c = b - 1536; K = 512; N = 1024; src = f2w + (size_t)id * 512 * 1024;
      n0 = (c & 31) * 32; k0 = (c >> 5) * 32; dst = w2;
    }
    int tx = tid & 31, ty = tid >> 5;
#pragma unroll
    for (int j = 0; j < 4; ++j) {
      int kr = k0 + ty + j * 8;
      tile[ty + j * 8][tx] = src[(size_t)kr * N + n0 + tx];
    }
    __syncthreads();
#pragma unroll
    for (int j = 0; j < 4; ++j) {
      int nr = n0 + ty + j * 8;
      dst[(size_t)nr * K + k0 + tx] = f2bf(tile[tx][ty + j * 8]);
    }
    return;
  }
  // ---- LN1 ----
  int row = b - 2048, t = tid;
  const float* g = g_base + (size_t)id * HDIM;
  const float* bb = b_base + (size_t)id * HDIM;
  u16x4_t xv = ((const u16x4_t*)(x + (size_t)row * HDIM))[t];
  float v0 = b2f(xv.x), v1 = b2f(xv.y), v2 = b2f(xv.z), v3 = b2f(xv.w);
  float s = v0 + v1 + v2 + v3;
  float q = v0 * v0 + v1 * v1 + v2 * v2 + v3 * v3;
  for (int o = 32; o; o >>= 1) { s += __shfl_down(s, o); q += __shfl_down(q, o); }
  float* ss = sh; float* sq = sh + 8;
  int wave = t >> 6, lane = t & 63;
  if (lane == 0) { ss[wave] = s; sq[wave] = q; }
  __syncthreads();
  if (t == 0) {
    float S = ss[0] + ss[1] + ss[2] + ss[3];
    float Q = sq[0] + sq[1] + sq[2] + sq[3];
    ss[0] = S * (1.0f / 1024.0f);
    sq[0] = Q * (1.0f / 1024.0f);
  }
  __syncthreads();
  float mean = ss[0];
  float var = sq[0] - mean * mean;
  float rs = rsqrtf(var + 1e-5f);
  float4 gv = ((const float4*)g)[t];
  float4 bv = ((const float4*)bb)[t];
  u16x4_t o4;
  o4.x = f2bf((v0 - mean) * rs * gv.x + bv.x);
  o4.y = f2bf((v1 - mean) * rs * gv.y + bv.y);
  o4.z = f2bf((v2 - mean) * rs * gv.z + bv.z);
  o4.w = f2bf((v3 - mean) * rs * gv.w + bv.w);
  ((u16x4_t*)(abf + (size_t)row * HDIM))[t] = o4;
}

// --------------------------- layernorm -> bf16 (ln2) ------------------------
__global__ void ln_kernel(const u16* __restrict__ x,
                          const float* __restrict__ g_base,
                          const float* __restrict__ b_base,
                          const int* __restrict__ idx_ptr, int slot,
                          u16* __restrict__ out) {
  int row = blockIdx.x, t = threadIdx.x;     // 256 threads, 4 elems each
  size_t off = (size_t)idx_ptr[slot] * HDIM;
  const float* g = g_base + off;
  const float* b = b_base + off;
  u16x4_t xv = ((const u16x4_t*)(x + (size_t)row * HDIM))[t];
  float v0 = b2f(xv.x), v1 = b2f(xv.y), v2 = b2f(xv.z), v3 = b2f(xv.w);
  float s = v0 + v1 + v2 + v3;
  float q = v0 * v0 + v1 * v1 + v2 * v2 + v3 * v3;
  for (int o = 32; o; o >>= 1) { s += __shfl_down(s, o); q += __shfl_down(q, o); }
  __shared__ float ss[4], sq[4];
  int wave = t >> 6, lane = t & 63;
  if (lane == 0) { ss[wave] = s; sq[wave] = q; }
  __syncthreads();
  if (t == 0) {
    float S = ss[0] + ss[1] + ss[2] + ss[3];
    float Q = sq[0] + sq[1] + sq[2] + sq[3];
    ss[0] = S * (1.0f / 1024.0f);
    sq[0] = Q * (1.0f / 1024.0f);
  }
  __syncthreads();
  float mean = ss[0];
  float var = sq[0] - mean * mean;
  float rs = rsqrtf(var + 1e-5f);
  float4 gv = ((const float4*)g)[t];
  float4 bv = ((const float4*)b)[t];
  u16x4_t o4;
  o4.x = f2bf((v0 - mean) * rs * gv.x + bv.x);
  o4.y = f2bf((v1 - mean) * rs * gv.y + bv.y);
  o4.z = f2bf((v2 - mean) * rs * gv.z + bv.z);
  o4.w = f2bf((v3 - mean) * rs * gv.w + bv.w);
  ((u16x4_t*)(out + (size_t)row * HDIM))[t] = o4;
}

// --------------------------- layer GEMM (BK=128) ----------------------------
// C[M=4096][N] = A[M][K](bf16) * Bt[N][K](bf16)^T, fp32 acc, fused epilogues.
// BK=128, 256 threads = 4 waves (2Mx2N), 16B-group XOR swizzle. Row-major
// epilogue. Residual x is bf16 (fp32 math in-register).
// EPI 0: x = bf16(x + 0.5*(c+bias)*scale)       (attn; N==H)
// EPI 1: outb = bf16(gelu(c+bias))              (ff1)
// EPI 2: x = bf16((x + 0.5*(c+bias)) * lscale)  (ff2)
template <int BM, int BN, int EPI>
__global__ __launch_bounds__(256) void gemm_layer(
    const u16* __restrict__ A, const u16* __restrict__ Bt, int N, int K,
    const float* __restrict__ bias_base, const int* __restrict__ idx_ptr,
    int slot, int bias_stride, const float* __restrict__ scale,
    u16* __restrict__ xres, u16* __restrict__ outb, float lscale) {
  constexpr int TM = BM / 2, TN = BN / 2;
  constexpr int FM = TM / 16, FN = TN / 16;
  constexpr int NLD = (BM + BN) / 16;       // gloads/thread/step (BK=128)
  __shared__ __align__(16) u16 lds[(BM + BN) * 128];

  const int tid = threadIdx.x, wave = tid >> 6, lane = tid & 63;
  const int m0 = blockIdx.y * BM, n0 = blockIdx.x * BN;
  const int wm = wave >> 1, wn = wave & 1;
  const int fr = lane & 15, g = lane >> 4;
  const float* bias =
      bias_base + (idx_ptr ? (size_t)idx_ptr[slot] * bias_stride : 0);

  const u16* gbase[NLD];
  unsigned ldsoff[NLD];
#pragma unroll
  for (int j = 0; j < NLD; ++j) {
    int lo = (tid + j * 256) * 16;        // byte offset in (BM+BN)*256 tile
    int q = (lo >> 4) & 15;               // 16B-group within 256B row
    if (lo < BM * 256) {
      int row = lo >> 8;
      gbase[j] = A + (size_t)(m0 + row) * K + (q ^ (row & 7)) * 8;
    } else {
      int bo = lo - BM * 256;
      int row = bo >> 8;
      gbase[j] = Bt + (size_t)(n0 + row) * K + (q ^ (row & 7)) * 8;
    }
    ldsoff[j] = (unsigned)(lo >> 1);
  }

  unsigned offA[FM][4], offB[FN][4];
#pragma unroll
  for (int mi = 0; mi < FM; ++mi)
#pragma unroll
    for (int kk = 0; kk < 4; ++kk)
      offA[mi][kk] = (unsigned)((wm * TM + mi * 16 + fr) * 256 +
                                (((kk * 4 + g) ^ (fr & 7)) << 4));
#pragma unroll
  for (int ni = 0; ni < FN; ++ni)
#pragma unroll
    for (int kk = 0; kk < 4; ++kk)
      offB[ni][kk] = (unsigned)(BM * 256 + (wn * TN + ni * 16 + fr) * 256 +
                                (((kk * 4 + g) ^ (fr & 7)) << 4));

  f32x4 acc[FM][FN];
#pragma unroll
  for (int i = 0; i < FM; ++i)
#pragma unroll
    for (int j = 0; j < FN; ++j) acc[i][j] = (f32x4){0.f, 0.f, 0.f, 0.f};

  for (int kt = 0; kt < K; kt += 128) {
#pragma unroll
    for (int j = 0; j < NLD; ++j) gload16(gbase[j] + kt, lds + ldsoff[j]);
    __syncthreads();
#pragma unroll
    for (int kk = 0; kk < 4; ++kk) {
      bf16x8 af[FM], bf[FN];
#pragma unroll
      for (int mi = 0; mi < FM; ++mi)
        af[mi] = *(const bf16x8*)((const char*)lds + offA[mi][kk]);
#pragma unroll
      for (int ni = 0; ni < FN; ++ni)
        bf[ni] = *(const bf16x8*)((const char*)lds + offB[ni][kk]);
#pragma unroll
      for (int mi = 0; mi < FM; ++mi)
#pragma unroll
        for (int ni = 0; ni < FN; ++ni)
          acc[mi][ni] = __builtin_amdgcn_mfma_f32_16x16x32_bf16(
              af[mi], bf[ni], acc[mi][ni], 0, 0, 0);
    }
    __syncthreads();
  }

  // ---- epilogue: row-major order, ni innermost ----
  const int rb = g * 4, cn = fr;
  float bvv[FN], svv[FN];
#pragma unroll
  for (int ni = 0; ni < FN; ++ni) {
    int n = n0 + wn * TN + ni * 16 + cn;
    bvv[ni] = bias[n];
    svv[ni] = (EPI == 0) ? scale[n] : 0.f;
  }
#pragma unroll
  for (int mi = 0; mi < FM; ++mi) {
#pragma unroll
    for (int r = 0; r < 4; ++r) {
      int m = m0 + wm * TM + mi * 16 + rb + r;
      size_t base = (size_t)m * N + n0 + wn * TN + cn;
#pragma unroll
      for (int ni = 0; ni < FN; ++ni) {
        float c = acc[mi][ni][r] + bvv[ni];
        size_t o = base + ni * 16;
        if (EPI == 0) {
          float xv = b2f(xres[o]);
          xres[o] = f2bf(xv + 0.5f * (c * svv[ni]));
        } else if (EPI == 1) {
          float ge = 0.5f * c * (1.0f + erff(c * 0.70710678118654752f));
          outb[o] = f2bf(ge);
        } else {
          float xv = b2f(xres[o]);
          xres[o] = f2bf((xv + 0.5f * c) * lscale);
        }
      }
    }
  }
}

// --------------------------- LM-head GEMM (128x128, 2 blk/CU) ---------------
// out[4096][32000] = x[4096][1024](bf16) @ lmT[32000][1024](bf16)^T + bias.
// 128x128 tile, 4 waves 2Mx2N (wave tile 64x64, acc=64 VGPR). BK=64,
// double-buffered 2x32 KB = 64 KB LDS -> 2 blocks/CU (cross-block overlap of
// barrier/VMW stalls). Per step: BARR_A; stage whole tile t+1 (8 gloads);
// VMW(8) counted (retires tile t); BARR_B; kk0+kk1 reads + 2x16 MFMA.
// 16B-group XOR swizzle, XCD chunking, row-major NT epilogue.
__global__ __launch_bounds__(256, 2) void gemm_lm(
    const u16* __restrict__ A, const u16* __restrict__ Bt,
    const float* __restrict__ bias, float* __restrict__ out) {
  constexpr int K = HDIM;      // 1024
  constexpr int N = VOC;       // 32000
  constexpr int NT = K / 64;   // 16 K-tiles
  __shared__ __align__(16) u16 smbuf[2 * 16384];   // 2 x 32 KB

  const int tid = threadIdx.x, wave = tid >> 6, lane = tid & 63;
  // XCD chunking over 8000 blocks (32 m x 250 n), m-fastest in-chunk.
  const int bid = blockIdx.x;
  const int vbid = (bid & 7) * 1000 + (bid >> 3);
  const int n0 = (vbid >> 5) * 128;
  const int m0 = (vbid & 31) * 128;
  const int wm = wave >> 1, wn = wave & 1;
  const int fr = lane & 15, g = lane >> 4;

  // staging: whole tile = (128 A rows + 128 B rows) x 128B = 32 KB, 8 loads/thr
  const u16* gb[8];
  unsigned lso[8];
#pragma unroll
  for (int j = 0; j < 8; ++j) {
    int lo = (tid + j * 256) * 16;
    int q = (lo >> 4) & 7;
    if (lo < 16384) {
      int row = lo >> 7;
      gb[j] = A + (size_t)(m0 + row) * K + (q ^ (row & 7)) * 8;
    } else {
      int bo = lo - 16384;
      int row = bo >> 7;
      gb[j] = Bt + (size_t)(n0 + row) * K + (q ^ (row & 7)) * 8;
    }
    lso[j] = (unsigned)(lo >> 1);
  }

  unsigned offA[4][2], offB[4][2];
#pragma unroll
  for (int mi = 0; mi < 4; ++mi)
#pragma unroll
    for (int kk = 0; kk < 2; ++kk)
      offA[mi][kk] = (unsigned)((wm * 64 + mi * 16 + fr) * 128 +
                                (((kk * 4 + g) ^ (fr & 7)) << 4));
#pragma unroll
  for (int ni = 0; ni < 4; ++ni)
#pragma unroll
    for (int kk = 0; kk < 2; ++kk)
      offB[ni][kk] = (unsigned)(16384 + (wn * 64 + ni * 16 + fr) * 128 +
                                (((kk * 4 + g) ^ (fr & 7)) << 4));

  f32x4 acc[4][4];
#pragma unroll
  for (int i = 0; i < 4; ++i)
#pragma unroll
    for (int j = 0; j < 4; ++j) acc[i][j] = (f32x4){0.f, 0.f, 0.f, 0.f};

  // prologue: stage tile 0 into buf0
#pragma unroll
  for (int j = 0; j < 8; ++j) gload16(gb[j], smbuf + lso[j]);

  for (int t = 0; t < NT; ++t) {
    const char* cb = (const char*)smbuf + (size_t)(t & 1) * 32768;
    u16* nb = smbuf + ((t + 1) & 1) * 16384;
    const int ko = (t + 1) * 64;
    BARR();                                // WAR: step t-1 reads done
    if (t + 1 < NT) {
#pragma unroll
      for (int j = 0; j < 8; ++j) gload16(gb[j] + ko, nb + lso[j]);
      VMW(8);                              // retire tile t; t+1 in flight
    } else {
      VMW(0);
    }
    BARR();                                // RAW: all waves' tile t retired
    // ---- kk0 ----
    {
      bf16x8 af[4], bf[4];
#pragma unroll
      for (int mi = 0; mi < 4; ++mi)
        af[mi] = *(const bf16x8*)(cb + offA[mi][0]);
#pragma unroll
      for (int ni = 0; ni < 4; ++ni)
        bf[ni] = *(const bf16x8*)(cb + offB[ni][0]);
      __builtin_amdgcn_s_setprio(1);
#pragma unroll
      for (int mi = 0; mi < 4; ++mi)
#pragma unroll
        for (int ni = 0; ni < 4; ++ni)
          acc[mi][ni] = __builtin_amdgcn_mfma_f32_16x16x32_bf16(
              af[mi], bf[ni], acc[mi][ni], 0, 0, 0);
      __builtin_amdgcn_s_setprio(0);
    }
    // ---- kk1 ----
    {
      bf16x8 af[4], bf[4];
#pragma unroll
      for (int mi = 0; mi < 4; ++mi)
        af[mi] = *(const bf16x8*)(cb + offA[mi][1]);
#pragma unroll
      for (int ni = 0; ni < 4; ++ni)
        bf[ni] = *(const bf16x8*)(cb + offB[ni][1]);
      __builtin_amdgcn_s_setprio(1);
#pragma unroll
      for (int mi = 0; mi < 4; ++mi)
#pragma unroll
        for (int ni = 0; ni < 4; ++ni)
          acc[mi][ni] = __builtin_amdgcn_mfma_f32_16x16x32_bf16(
              af[mi], bf[ni], acc[mi][ni], 0, 0, 0);
      __builtin_amdgcn_s_setprio(0);
    }
  }

  // ---- epilogue: row-major, ni innermost -> contiguous NT stores ----------
  const int rb = g * 4, cn = fr;
  float bvv[4];
#pragma unroll
  for (int ni = 0; ni < 4; ++ni) bvv[ni] = bias[n0 + wn * 64 + ni * 16 + cn];
#pragma unroll
  for (int mi = 0; mi < 4; ++mi) {
#pragma unroll
    for (int r = 0; r < 4; ++r) {
      int m = m0 + wm * 64 + mi * 16 + rb + r;
      float* orow = out + (size_t)m * N + n0 + wn * 64 + cn;
#pragma unroll
      for (int ni = 0; ni < 4; ++ni)
        __builtin_nontemporal_store(acc[mi][ni][r] + bvv[ni], orow + ni * 16);
    }
  }
}

// --------------------------- launch ----------------------------------------
extern "C" void kernel_launch(void* const* d_in, const int* in_sizes, int n_in,
                              void* d_out, int out_size, void* d_ws,
                              size_t ws_size, hipStream_t stream) {
  (void)in_sizes; (void)n_in; (void)out_size; (void)ws_size;
  const int*   ids    = (const int*)d_in[0];
  const float* emb    = (const float*)d_in[1];
  const float* pos    = (const float*)d_in[2];
  const float* tf     = (const float*)d_in[3];
  const float* lm_w   = (const float*)d_in[4];
  const float* lm_b   = (const float*)d_in[5];
  const float* sel_w  = (const float*)d_in[6];
  const float* sel_b  = (const float*)d_in[7];
  const float* g1     = (const float*)d_in[8];
  const float* b1     = (const float*)d_in[9];
  const float* attn_w = (const float*)d_in[10];
  const float* attn_b = (const float*)d_in[11];
  const float* g2     = (const float*)d_in[12];
  const float* b2     = (const float*)d_in[13];
  const float* ff1_w  = (const float*)d_in[14];
  const float* ff1_b  = (const float*)d_in[15];
  const float* ff2_w  = (const float*)d_in[16];
  const float* ff2_b  = (const float*)d_in[17];
  const float* tg     = (const float*)d_in[18];
  float* out = (float*)d_out;

  char* ws = (char*)d_ws;
  u16*   x       = (u16*)(ws + 0);            // 8 MB bf16 residual
  u16*   abf     = (u16*)(ws + 16777216);     // 8 MB bf16 LN out
  u16*   tbuf    = (u16*)(ws + 25165824);     // 4 MB bf16 gelu out
  u16*   wA      = (u16*)(ws + 29360128);     // 2 MB attn W^T
  u16*   w1      = (u16*)(ws + 31457280);     // 1 MB ff1 W^T
  u16*   w2      = (u16*)(ws + 32505856);     // 1 MB ff2 W^T
  u16*   lmT     = (u16*)(ws + 33554432);     // 62.5 MB lm W^T
  float* partial = (float*)(ws + 99090432);   // 256 KB router colsum
  float* scalev  = (float*)(ws + 99352576);   // 8 KB torsion scales
  int*   idx     = (int*)(ws + 99360768);     // 8 B top-2 indices

  embed_lm_kernel<<<MTOT + VOC, 256, 0, stream>>>(ids, emb, pos, x, lm_w, lmT);

  for (int l = 0; l < NLAYER; ++l) {
    colsum_kernel<<<64, 256, 0, stream>>>(x, partial);
    router_finalize<<<1, 1024, 0, stream>>>(
        partial, sel_w + (size_t)l * HDIM * NBLK, sel_b + l * NBLK,
        tg + (size_t)l * NBLK * HDIM, tf, idx, scalev);
    const float* aw_l  = attn_w + (size_t)l * NBLK * HDIM * HDIM;
    const float* f1w_l = ff1_w + (size_t)l * NBLK * HDIM * HFF;
    const float* f2w_l = ff2_w + (size_t)l * NBLK * HFF * HDIM;
    for (int k = 0; k < 2; ++k) {
      prep_kernel<<<2048 + MTOT, 256, 0, stream>>>(
          aw_l, f1w_l, f2w_l, idx, k, wA, w1, w2, x,
          g1 + (size_t)l * NBLK * HDIM, b1 + (size_t)l * NBLK * HDIM, abf);
      gemm_layer<128, 64, 0><<<dim3(16, 32), 256, 0, stream>>>(
          abf, wA, HDIM, HDIM, attn_b + (size_t)l * NBLK * HDIM, idx, k, HDIM,
          scalev + k * HDIM, x, nullptr, 1.0f);
      ln_kernel<<<MTOT, 256, 0, stream>>>(x, g2 + (size_t)l * NBLK * HDIM,
                                          b2 + (size_t)l * NBLK * HDIM, idx, k,
                                          abf);
      gemm_layer<64, 64, 1><<<dim3(8, 64), 256, 0, stream>>>(
          abf, w1, HFF, HDIM, ff1_b + (size_t)l * NBLK * HFF, idx, k, HFF,
          nullptr, nullptr, tbuf, 1.0f);
      float lsc = (k == 1) ? 1.5f : 1.0f;
      gemm_layer<128, 64, 2><<<dim3(16, 32), 256, 0, stream>>>(
          tbuf, w2, HDIM, HFF, ff2_b + (size_t)l * NBLK * HDIM, idx, k, HDIM,
          nullptr, x, nullptr, lsc);
    }
  }

  gemm_lm<<<8000, 256, 0, stream>>>(x, lmT, lm_b, out);
}

// Round 18
// 938.826 us; speedup vs baseline: 1.1198x; 1.1198x over previous
//
#include <hip/hip_runtime.h>

// ---------------------------------------------------------------------------
// UltimateTNN: MoE-ish transformer forward on MI355X (gfx950).
// B=8 S=512 H=1024 HF=512 V=32000 L=4 NB=8 K=2, M = B*S = 4096.
// Round 18: revert round-17 regression (128^2 tile halved arithmetic
// intensity -> FETCH 1.04 GB, HBM-bound). Back to round-16 best (924 us):
// bf16 residual; BK=128 layer GEMMs; 256^2 4-phase gemm_lm (closed at its
// measured plateau ~315 us after 7 variants); merged prep/embed launches.
// ---------------------------------------------------------------------------

typedef unsigned short u16;
typedef short bf16x8 __attribute__((ext_vector_type(8)));
typedef float f32x4 __attribute__((ext_vector_type(4)));

struct __align__(8) u16x4_t { u16 x, y, z, w; };

#define MTOT 4096
#define HDIM 1024
#define HFF  512
#define VOC  32000
#define NLAYER 4
#define NBLK 8

#define VMW(n) asm volatile("s_waitcnt vmcnt(" #n ")" ::: "memory")
#define BARR() do { asm volatile("" ::: "memory"); __builtin_amdgcn_s_barrier(); asm volatile("" ::: "memory"); } while (0)

__device__ __forceinline__ u16 f2bf(float f) {
  unsigned u = __float_as_uint(f);
  unsigned r = u + 0x7FFFu + ((u >> 16) & 1u);
  return (u16)(r >> 16);
}

__device__ __forceinline__ float b2f(u16 v) {
  return __uint_as_float(((unsigned)v) << 16);
}

__device__ __forceinline__ float sigmoidf_(float z) {
  return 1.0f / (1.0f + expf(-z));
}

__device__ __forceinline__ void gload16(const void* g, void* l) {
  __builtin_amdgcn_global_load_lds(
      (const __attribute__((address_space(1))) void*)g,
      (__attribute__((address_space(3))) void*)l, 16, 0, 0);
}

// ---------------- embed + lm_w transpose (merged, independent) --------------
__global__ void embed_lm_kernel(const int* __restrict__ ids,
                                const float* __restrict__ emb,
                                const float* __restrict__ pos,
                                u16* __restrict__ x,
                                const float* __restrict__ lm_w,
                                u16* __restrict__ lmT) {
  __shared__ float tile[32][33];
  int b = blockIdx.x, tid = threadIdx.x;
  if (b < MTOT) {
    int s = b & 511;
    int id = ids[b];
    float4 e = ((const float4*)(emb + (size_t)id * HDIM))[tid];
    float4 p = ((const float4*)(pos + (size_t)s * HDIM))[tid];
    u16x4_t r;
    r.x = f2bf(e.x + p.x); r.y = f2bf(e.y + p.y);
    r.z = f2bf(e.z + p.z); r.w = f2bf(e.w + p.w);
    ((u16x4_t*)(x + (size_t)b * HDIM))[tid] = r;
    return;
  }
  int c = b - MTOT;                 // 0..31999
  int n0 = (c % 1000) * 32, k0 = (c / 1000) * 32;
  int tx = tid & 31, ty = tid >> 5; // (32,8)
#pragma unroll
  for (int j = 0; j < 4; ++j) {
    int kr = k0 + ty + j * 8;
    tile[ty + j * 8][tx] = lm_w[(size_t)kr * VOC + n0 + tx];
  }
  __syncthreads();
#pragma unroll
  for (int j = 0; j < 4; ++j) {
    int nr = n0 + ty + j * 8;
    lmT[(size_t)nr * HDIM + k0 + tx] = f2bf(tile[tx][ty + j * 8]);
  }
}

// --------------------------- router ----------------------------------------
__global__ void colsum_kernel(const u16* __restrict__ x, float* __restrict__ partial) {
  int j = blockIdx.x;            // 0..63
  int t = threadIdx.x;           // 0..255 (4 elems each)
  float4 s; s.x = 0.f; s.y = 0.f; s.z = 0.f; s.w = 0.f;
  for (int r = 0; r < 8; ++r) {
    u16x4_t a = ((const u16x4_t*)(x + (size_t)(j * 8 + r) * HDIM))[t];
    s.x += b2f(a.x); s.y += b2f(a.y); s.z += b2f(a.z); s.w += b2f(a.w);
  }
  ((float4*)(partial + (size_t)j * HDIM))[t] = s;
}

__global__ void router_finalize(const float* __restrict__ partial,
                                const float* __restrict__ selw,   // [H][NB]
                                const float* __restrict__ selb,   // [NB]
                                const float* __restrict__ tg_l,   // [NB][H]
                                const float* __restrict__ tf,     // [H]
                                int* __restrict__ idx_out,        // [2]
                                float* __restrict__ scale_out) {  // [2][H]
  int t = threadIdx.x;           // 0..1023
  float s = 0.f;
  for (int j = 0; j < 64; ++j) s += partial[(size_t)j * HDIM + t];
  float mean = s * (1.0f / 512.0f);
  __shared__ float sm[HDIM];
  __shared__ float sc[NBLK];
  __shared__ int sidx[2];
  sm[t] = mean;
  __syncthreads();
  int wave = t >> 6, lane = t & 63;
  if (wave < NBLK) {
    float p = 0.f;
    for (int h = lane; h < HDIM; h += 64) p += sm[h] * selw[h * NBLK + wave];
    for (int o = 32; o; o >>= 1) p += __shfl_down(p, o);
    if (lane == 0) sc[wave] = p;
  }
  __syncthreads();
  if (t == 0) {
    float adj[NBLK];
    for (int i = 0; i < NBLK; ++i) {
      float z = sc[i] + selb[i];
      adj[i] = sigmoidf_(z) * 0.7f + 0.15f;   // PRIORITY=0.5 * 0.3
    }
    int i0 = 0;
    for (int i = 1; i < NBLK; ++i) if (adj[i] > adj[i0]) i0 = i;
    int i1 = -1;
    for (int i = 0; i < NBLK; ++i) {
      if (i == i0) continue;
      if (i1 < 0 || adj[i] > adj[i1]) i1 = i;
    }
    idx_out[0] = i0; idx_out[1] = i1;
    sidx[0] = i0; sidx[1] = i1;
  }
  __syncthreads();
  for (int k = 0; k < 2; ++k) {
    int id = sidx[k];
    float z = tg_l[(size_t)id * HDIM + t];
    scale_out[k * HDIM + t] = 1.0f + sigmoidf_(z) * tf[t];
  }
}

// --------- prep: weight transpose (slot k) + LN1 (slot k), one launch ------
__global__ void prep_kernel(const float* __restrict__ aw,
                            const float* __restrict__ f1w,
                            const float* __restrict__ f2w,
                            const int* __restrict__ idx, int slot,
                            u16* __restrict__ wA, u16* __restrict__ w1,
                            u16* __restrict__ w2,
                            const u16* __restrict__ x,
                            const float* __restrict__ g_base,
                            const float* __restrict__ b_base,
                            u16* __restrict__ abf) {
  __shared__ float sh[32 * 33];
  int b = blockIdx.x, tid = threadIdx.x;
  int id = idx[slot];
  if (b < 2048) {
    float (*tile)[33] = (float(*)[33])sh;
    const float* src; u16* dst; int K, N, n0, k0;
    if (b < 1024) {
      K = 1024; N = 1024; src = aw + (size_t)id * 1024 * 1024;
      n0 = (b & 31) * 32; k0 = (b >> 5) * 32; dst = wA;
    } else if (b < 1536) {
      int c = b - 1024; K = 1024; N = 512; src = f1w + (size_t)id * 1024 * 512;
      n0 = (c & 15) * 32; k0 = (c >> 4) * 32; dst = w1;
    } else {
      int c = b - 1536; K = 512; N = 1024; src = f2w + (size_t)id * 512 * 1024;
      n0 = (c & 31) * 32; k0 = (c >> 5) * 32; dst = w2;
    }
    int tx = tid & 31, ty = tid >> 5;
#pragma unroll
    for (int j = 0; j < 4; ++j) {
      int kr = k0 + ty + j * 8;
      tile[ty + j * 8][tx] = src[(size_t)kr * N + n0 + tx];
    }
    __syncthreads();
#pragma unroll
    for (int j = 0; j < 4; ++j) {
      int nr = n0 + ty + j * 8;
      dst[(size_t)nr * K + k0 + tx] = f2bf(tile[tx][ty + j * 8]);
    }
    return;
  }
  // ---- LN1 ----
  int row = b - 2048, t = tid;
  const float* g = g_base + (size_t)id * HDIM;
  const float* bb = b_base + (size_t)id * HDIM;
  u16x4_t xv = ((const u16x4_t*)(x + (size_t)row * HDIM))[t];
  float v0 = b2f(xv.x), v1 = b2f(xv.y), v2 = b2f(xv.z), v3 = b2f(xv.w);
  float s = v0 + v1 + v2 + v3;
  float q = v0 * v0 + v1 * v1 + v2 * v2 + v3 * v3;
  for (int o = 32; o; o >>= 1) { s += __shfl_down(s, o); q += __shfl_down(q, o); }
  float* ss = sh; float* sq = sh + 8;
  int wave = t >> 6, lane = t & 63;
  if (lane == 0) { ss[wave] = s; sq[wave] = q; }
  __syncthreads();
  if (t == 0) {
    float S = ss[0] + ss[1] + ss[2] + ss[3];
    float Q = sq[0] + sq[1] + sq[2] + sq[3];
    ss[0] = S * (1.0f / 1024.0f);
    sq[0] = Q * (1.0f / 1024.0f);
  }
  __syncthreads();
  float mean = ss[0];
  float var = sq[0] - mean * mean;
  float rs = rsqrtf(var + 1e-5f);
  float4 gv = ((const float4*)g)[t];
  float4 bv = ((const float4*)bb)[t];
  u16x4_t o4;
  o4.x = f2bf((v0 - mean) * rs * gv.x + bv.x);
  o4.y = f2bf((v1 - mean) * rs * gv.y + bv.y);
  o4.z = f2bf((v2 - mean) * rs * gv.z + bv.z);
  o4.w = f2bf((v3 - mean) * rs * gv.w + bv.w);
  ((u16x4_t*)(abf + (size_t)row * HDIM))[t] = o4;
}

// --------------------------- layernorm -> bf16 (ln2) ------------------------
__global__ void ln_kernel(const u16* __restrict__ x,
                          const float* __restrict__ g_base,
                          const float* __restrict__ b_base,
                          const int* __restrict__ idx_ptr, int slot,
                          u16* __restrict__ out) {
  int row = blockIdx.x, t = threadIdx.x;     // 256 threads, 4 elems each
  size_t off = (size_t)idx_ptr[slot] * HDIM;
  const float* g = g_base + off;
  const float* b = b_base + off;
  u16x4_t xv = ((const u16x4_t*)(x + (size_t)row * HDIM))[t];
  float v0 = b2f(xv.x), v1 = b2f(xv.y), v2 = b2f(xv.z), v3 = b2f(xv.w);
  float s = v0 + v1 + v2 + v3;
  float q = v0 * v0 + v1 * v1 + v2 * v2 + v3 * v3;
  for (int o = 32; o; o >>= 1) { s += __shfl_down(s, o); q += __shfl_down(q, o); }
  __shared__ float ss[4], sq[4];
  int wave = t >> 6, lane = t & 63;
  if (lane == 0) { ss[wave] = s; sq[wave] = q; }
  __syncthreads();
  if (t == 0) {
    float S = ss[0] + ss[1] + ss[2] + ss[3];
    float Q = sq[0] + sq[1] + sq[2] + sq[3];
    ss[0] = S * (1.0f / 1024.0f);
    sq[0] = Q * (1.0f / 1024.0f);
  }
  __syncthreads();
  float mean = ss[0];
  float var = sq[0] - mean * mean;
  float rs = rsqrtf(var + 1e-5f);
  float4 gv = ((const float4*)g)[t];
  float4 bv = ((const float4*)b)[t];
  u16x4_t o4;
  o4.x = f2bf((v0 - mean) * rs * gv.x + bv.x);
  o4.y = f2bf((v1 - mean) * rs * gv.y + bv.y);
  o4.z = f2bf((v2 - mean) * rs * gv.z + bv.z);
  o4.w = f2bf((v3 - mean) * rs * gv.w + bv.w);
  ((u16x4_t*)(out + (size_t)row * HDIM))[t] = o4;
}

// --------------------------- layer GEMM (BK=128) ----------------------------
// C[M=4096][N] = A[M][K](bf16) * Bt[N][K](bf16)^T, fp32 acc, fused epilogues.
// BK=128, 256 threads = 4 waves (2Mx2N), 16B-group XOR swizzle. Row-major
// epilogue. Residual x is bf16 (fp32 math in-register).
// EPI 0: x = bf16(x + 0.5*(c+bias)*scale)       (attn; N==H)
// EPI 1: outb = bf16(gelu(c+bias))              (ff1)
// EPI 2: x = bf16((x + 0.5*(c+bias)) * lscale)  (ff2)
template <int BM, int BN, int EPI>
__global__ __launch_bounds__(256) void gemm_layer(
    const u16* __restrict__ A, const u16* __restrict__ Bt, int N, int K,
    const float* __restrict__ bias_base, const int* __restrict__ idx_ptr,
    int slot, int bias_stride, const float* __restrict__ scale,
    u16* __restrict__ xres, u16* __restrict__ outb, float lscale) {
  constexpr int TM = BM / 2, TN = BN / 2;
  constexpr int FM = TM / 16, FN = TN / 16;
  constexpr int NLD = (BM + BN) / 16;       // gloads/thread/step (BK=128)
  __shared__ __align__(16) u16 lds[(BM + BN) * 128];

  const int tid = threadIdx.x, wave = tid >> 6, lane = tid & 63;
  const int m0 = blockIdx.y * BM, n0 = blockIdx.x * BN;
  const int wm = wave >> 1, wn = wave & 1;
  const int fr = lane & 15, g = lane >> 4;
  const float* bias =
      bias_base + (idx_ptr ? (size_t)idx_ptr[slot] * bias_stride : 0);

  const u16* gbase[NLD];
  unsigned ldsoff[NLD];
#pragma unroll
  for (int j = 0; j < NLD; ++j) {
    int lo = (tid + j * 256) * 16;        // byte offset in (BM+BN)*256 tile
    int q = (lo >> 4) & 15;               // 16B-group within 256B row
    if (lo < BM * 256) {
      int row = lo >> 8;
      gbase[j] = A + (size_t)(m0 + row) * K + (q ^ (row & 7)) * 8;
    } else {
      int bo = lo - BM * 256;
      int row = bo >> 8;
      gbase[j] = Bt + (size_t)(n0 + row) * K + (q ^ (row & 7)) * 8;
    }
    ldsoff[j] = (unsigned)(lo >> 1);
  }

  unsigned offA[FM][4], offB[FN][4];
#pragma unroll
  for (int mi = 0; mi < FM; ++mi)
#pragma unroll
    for (int kk = 0; kk < 4; ++kk)
      offA[mi][kk] = (unsigned)((wm * TM + mi * 16 + fr) * 256 +
                                (((kk * 4 + g) ^ (fr & 7)) << 4));
#pragma unroll
  for (int ni = 0; ni < FN; ++ni)
#pragma unroll
    for (int kk = 0; kk < 4; ++kk)
      offB[ni][kk] = (unsigned)(BM * 256 + (wn * TN + ni * 16 + fr) * 256 +
                                (((kk * 4 + g) ^ (fr & 7)) << 4));

  f32x4 acc[FM][FN];
#pragma unroll
  for (int i = 0; i < FM; ++i)
#pragma unroll
    for (int j = 0; j < FN; ++j) acc[i][j] = (f32x4){0.f, 0.f, 0.f, 0.f};

  for (int kt = 0; kt < K; kt += 128) {
#pragma unroll
    for (int j = 0; j < NLD; ++j) gload16(gbase[j] + kt, lds + ldsoff[j]);
    __syncthreads();
#pragma unroll
    for (int kk = 0; kk < 4; ++kk) {
      bf16x8 af[FM], bf[FN];
#pragma unroll
      for (int mi = 0; mi < FM; ++mi)
        af[mi] = *(const bf16x8*)((const char*)lds + offA[mi][kk]);
#pragma unroll
      for (int ni = 0; ni < FN; ++ni)
        bf[ni] = *(const bf16x8*)((const char*)lds + offB[ni][kk]);
#pragma unroll
      for (int mi = 0; mi < FM; ++mi)
#pragma unroll
        for (int ni = 0; ni < FN; ++ni)
          acc[mi][ni] = __builtin_amdgcn_mfma_f32_16x16x32_bf16(
              af[mi], bf[ni], acc[mi][ni], 0, 0, 0);
    }
    __syncthreads();
  }

  // ---- epilogue: row-major order, ni innermost ----
  const int rb = g * 4, cn = fr;
  float bvv[FN], svv[FN];
#pragma unroll
  for (int ni = 0; ni < FN; ++ni) {
    int n = n0 + wn * TN + ni * 16 + cn;
    bvv[ni] = bias[n];
    svv[ni] = (EPI == 0) ? scale[n] : 0.f;
  }
#pragma unroll
  for (int mi = 0; mi < FM; ++mi) {
#pragma unroll
    for (int r = 0; r < 4; ++r) {
      int m = m0 + wm * TM + mi * 16 + rb + r;
      size_t base = (size_t)m * N + n0 + wn * TN + cn;
#pragma unroll
      for (int ni = 0; ni < FN; ++ni) {
        float c = acc[mi][ni][r] + bvv[ni];
        size_t o = base + ni * 16;
        if (EPI == 0) {
          float xv = b2f(xres[o]);
          xres[o] = f2bf(xv + 0.5f * (c * svv[ni]));
        } else if (EPI == 1) {
          float ge = 0.5f * c * (1.0f + erff(c * 0.70710678118654752f));
          outb[o] = f2bf(ge);
        } else {
          float xv = b2f(xres[o]);
          xres[o] = f2bf((xv + 0.5f * c) * lscale);
        }
      }
    }
  }
}

// --------------------------- LM-head GEMM (round-12 best) -------------------
// out[4096][32000] = x[4096][1024](bf16) @ lmT[32000][1024](bf16)^T + bias.
// 256x256 tile, 8 waves 2Mx4N. BK=64, double-buffered, 4 phases; units
// aligned to phase reads; VMW(2)+BARR at P1/P2 only. Swizzle, XCD chunking,
// row-major NT epilogue. Closed at measured plateau (~315 us, 7 variants).
__global__ __launch_bounds__(512, 2) void gemm_lm(
    const u16* __restrict__ A, const u16* __restrict__ Bt,
    const float* __restrict__ bias, float* __restrict__ out) {
  constexpr int K = HDIM;      // 1024
  constexpr int N = VOC;       // 32000
  constexpr int NT = K / 64;   // 16 K-tiles
  __shared__ __align__(16) u16 smbuf[2 * 32768];   // 2 x 64 KB

  const int tid = threadIdx.x, wid = tid >> 6, lane = tid & 63;
  const int bid = blockIdx.x;
  const int vbid = (bid & 7) * 250 + (bid >> 3);
  const int n0 = (vbid >> 4) * 256;
  const int m0 = (vbid & 15) * 256;
  const int wm = wid >> 2, wn = wid & 3;   // 2 x 4 waves
  const int fr = lane & 15, g = lane >> 4;

  const int r0 = tid >> 3, q = tid & 7;
  const int sg = (q ^ (r0 & 7)) * 8;         // u16 offset of swizzled group
  const u16* usrc[4][2];
  unsigned uoff[4][2];                       // u16 offsets within a buffer
  usrc[0][0] = Bt + (size_t)(n0 + r0) * K + sg;        uoff[0][0] = 16384u + tid * 8;
  usrc[0][1] = Bt + (size_t)(n0 + 64 + r0) * K + sg;   uoff[0][1] = 20480u + tid * 8;
  usrc[1][0] = Bt + (size_t)(n0 + 128 + r0) * K + sg;  uoff[1][0] = 24576u + tid * 8;
  usrc[1][1] = Bt + (size_t)(n0 + 192 + r0) * K + sg;  uoff[1][1] = 28672u + tid * 8;
  usrc[2][0] = A + (size_t)(m0 + r0) * K + sg;         uoff[2][0] = 0u + tid * 8;
  usrc[2][1] = A + (size_t)(m0 + 128 + r0) * K + sg;   uoff[2][1] = 8192u + tid * 8;
  usrc[3][0] = A + (size_t)(m0 + 64 + r0) * K + sg;    uoff[3][0] = 4096u + tid * 8;
  usrc[3][1] = A + (size_t)(m0 + 192 + r0) * K + sg;   uoff[3][1] = 12288u + tid * 8;

  unsigned offA[8][2], offB[4][2];
#pragma unroll
  for (int mi = 0; mi < 8; ++mi)
#pragma unroll
    for (int kk = 0; kk < 2; ++kk)
      offA[mi][kk] = (unsigned)((wm * 128 + mi * 16 + fr) * 128 +
                                (((kk * 4 + g) ^ (fr & 7)) << 4));
#pragma unroll
  for (int ni = 0; ni < 4; ++ni)
#pragma unroll
    for (int kk = 0; kk < 2; ++kk)
      offB[ni][kk] = (unsigned)(32768 + (wn * 64 + ni * 16 + fr) * 128 +
                                (((kk * 4 + g) ^ (fr & 7)) << 4));

  f32x4 acc[8][4];
#pragma unroll
  for (int i = 0; i < 8; ++i)
#pragma unroll
    for (int j = 0; j < 4; ++j) acc[i][j] = (f32x4){0.f, 0.f, 0.f, 0.f};

  // prologue: stage tile 0 into buf0 in ledger order u0,u1,u2,u3
#pragma unroll
  for (int u = 0; u < 4; ++u) {
    gload16(usrc[u][0], smbuf + uoff[u][0]);
    gload16(usrc[u][1], smbuf + uoff[u][1]);
  }

  for (int t = 0; t < NT; ++t) {
    const char* cb = (const char*)smbuf + (size_t)(t & 1) * 65536;
    u16* nb = smbuf + ((t + 1) & 1) * 32768;
    const int ko = (t + 1) * 64;
    const bool st = (t + 1 < NT);
    bf16x8 avl[4], avh[4], bv[4];
    // ---- P1: kk0, mi0-3 ---- needs u0,u1,u2 of tile t (VMW(2) leaves u3)
    VMW(2);
    BARR();
#pragma unroll
    for (int ni = 0; ni < 4; ++ni) bv[ni] = *(const bf16x8*)(cb + offB[ni][0]);
#pragma unroll
    for (int mi = 0; mi < 4; ++mi) avl[mi] = *(const bf16x8*)(cb + offA[mi][0]);
    if (st) {
      gload16(usrc[0][0] + ko, nb + uoff[0][0]);
      gload16(usrc[0][1] + ko, nb + uoff[0][1]);
    }
    __builtin_amdgcn_s_setprio(1);
#pragma unroll
    for (int mi = 0; mi < 4; ++mi)
#pragma unroll
      for (int ni = 0; ni < 4; ++ni)
        acc[mi][ni] = __builtin_amdgcn_mfma_f32_16x16x32_bf16(
            avl[mi], bv[ni], acc[mi][ni], 0, 0, 0);
    __builtin_amdgcn_s_setprio(0);
    // ---- P2: kk0, mi4-7 ---- needs u3 of tile t
    if (t < NT - 1) { VMW(2); } else { VMW(0); }
    BARR();
#pragma unroll
    for (int mi = 0; mi < 4; ++mi)
      avh[mi] = *(const bf16x8*)(cb + offA[4 + mi][0]);
    if (st) {
      gload16(usrc[1][0] + ko, nb + uoff[1][0]);
      gload16(usrc[1][1] + ko, nb + uoff[1][1]);
    }
    __builtin_amdgcn_s_setprio(1);
#pragma unroll
    for (int mi = 0; mi < 4; ++mi)
#pragma unroll
      for (int ni = 0; ni < 4; ++ni)
        acc[4 + mi][ni] = __builtin_amdgcn_mfma_f32_16x16x32_bf16(
            avh[mi], bv[ni], acc[4 + mi][ni], 0, 0, 0);
    __builtin_amdgcn_s_setprio(0);
    // ---- P3: kk1, mi0-3 ---- (resident)
#pragma unroll
    for (int ni = 0; ni < 4; ++ni) bv[ni] = *(const bf16x8*)(cb + offB[ni][1]);
#pragma unroll
    for (int mi = 0; mi < 4; ++mi) avl[mi] = *(const bf16x8*)(cb + offA[mi][1]);
    if (st) {
      gload16(usrc[2][0] + ko, nb + uoff[2][0]);
      gload16(usrc[2][1] + ko, nb + uoff[2][1]);
    }
    __builtin_amdgcn_s_setprio(1);
#pragma unroll
    for (int mi = 0; mi < 4; ++mi)
#pragma unroll
      for (int ni = 0; ni < 4; ++ni)
        acc[mi][ni] = __builtin_amdgcn_mfma_f32_16x16x32_bf16(
            avl[mi], bv[ni], acc[mi][ni], 0, 0, 0);
    __builtin_amdgcn_s_setprio(0);
    // ---- P4: kk1, mi4-7 ----
#pragma unroll
    for (int mi = 0; mi < 4; ++mi)
      avh[mi] = *(const bf16x8*)(cb + offA[4 + mi][1]);
    if (st) {
      gload16(usrc[3][0] + ko, nb + uoff[3][0]);
      gload16(usrc[3][1] + ko, nb + uoff[3][1]);
    }
    __builtin_amdgcn_s_setprio(1);
#pragma unroll
    for (int mi = 0; mi < 4; ++mi)
#pragma unroll
      for (int ni = 0; ni < 4; ++ni)
        acc[4 + mi][ni] = __builtin_amdgcn_mfma_f32_16x16x32_bf16(
            avh[mi], bv[ni], acc[4 + mi][ni], 0, 0, 0);
    __builtin_amdgcn_s_setprio(0);
  }

  // ---- epilogue: row-major, ni innermost -> 4 consecutive 64B chunks ------
  const int rb = g * 4, cn = fr;
  float bvv[4];
#pragma unroll
  for (int ni = 0; ni < 4; ++ni) bvv[ni] = bias[n0 + wn * 64 + ni * 16 + cn];
#pragma unroll
  for (int mi = 0; mi < 8; ++mi) {
#pragma unroll
    for (int r = 0; r < 4; ++r) {
      int m = m0 + wm * 128 + mi * 16 + rb + r;
      float* orow = out + (size_t)m * N + n0 + wn * 64 + cn;
#pragma unroll
      for (int ni = 0; ni < 4; ++ni)
        __builtin_nontemporal_store(acc[mi][ni][r] + bvv[ni], orow + ni * 16);
    }
  }
}

// --------------------------- launch ----------------------------------------
extern "C" void kernel_launch(void* const* d_in, const int* in_sizes, int n_in,
                              void* d_out, int out_size, void* d_ws,
                              size_t ws_size, hipStream_t stream) {
  (void)in_sizes; (void)n_in; (void)out_size; (void)ws_size;
  const int*   ids    = (const int*)d_in[0];
  const float* emb    = (const float*)d_in[1];
  const float* pos    = (const float*)d_in[2];
  const float* tf     = (const float*)d_in[3];
  const float* lm_w   = (const float*)d_in[4];
  const float* lm_b   = (const float*)d_in[5];
  const float* sel_w  = (const float*)d_in[6];
  const float* sel_b  = (const float*)d_in[7];
  const float* g1     = (const float*)d_in[8];
  const float* b1     = (const float*)d_in[9];
  const float* attn_w = (const float*)d_in[10];
  const float* attn_b = (const float*)d_in[11];
  const float* g2     = (const float*)d_in[12];
  const float* b2     = (const float*)d_in[13];
  const float* ff1_w  = (const float*)d_in[14];
  const float* ff1_b  = (const float*)d_in[15];
  const float* ff2_w  = (const float*)d_in[16];
  const float* ff2_b  = (const float*)d_in[17];
  const float* tg     = (const float*)d_in[18];
  float* out = (float*)d_out;

  char* ws = (char*)d_ws;
  u16*   x       = (u16*)(ws + 0);            // 8 MB bf16 residual
  u16*   abf     = (u16*)(ws + 16777216);     // 8 MB bf16 LN out
  u16*   tbuf    = (u16*)(ws + 25165824);     // 4 MB bf16 gelu out
  u16*   wA      = (u16*)(ws + 29360128);     // 2 MB attn W^T
  u16*   w1      = (u16*)(ws + 31457280);     // 1 MB ff1 W^T
  u16*   w2      = (u16*)(ws + 32505856);     // 1 MB ff2 W^T
  u16*   lmT     = (u16*)(ws + 33554432);     // 62.5 MB lm W^T
  float* partial = (float*)(ws + 99090432);   // 256 KB router colsum
  float* scalev  = (float*)(ws + 99352576);   // 8 KB torsion scales
  int*   idx     = (int*)(ws + 99360768);     // 8 B top-2 indices

  embed_lm_kernel<<<MTOT + VOC, 256, 0, stream>>>(ids, emb, pos, x, lm_w, lmT);

  for (int l = 0; l < NLAYER; ++l) {
    colsum_kernel<<<64, 256, 0, stream>>>(x, partial);
    router_finalize<<<1, 1024, 0, stream>>>(
        partial, sel_w + (size_t)l * HDIM * NBLK, sel_b + l * NBLK,
        tg + (size_t)l * NBLK * HDIM, tf, idx, scalev);
    const float* aw_l  = attn_w + (size_t)l * NBLK * HDIM * HDIM;
    const float* f1w_l = ff1_w + (size_t)l * NBLK * HDIM * HFF;
    const float* f2w_l = ff2_w + (size_t)l * NBLK * HFF * HDIM;
    for (int k = 0; k < 2; ++k) {
      prep_kernel<<<2048 + MTOT, 256, 0, stream>>>(
          aw_l, f1w_l, f2w_l, idx, k, wA, w1, w2, x,
          g1 + (size_t)l * NBLK * HDIM, b1 + (size_t)l * NBLK * HDIM, abf);
      gemm_layer<128, 64, 0><<<dim3(16, 32), 256, 0, stream>>>(
          abf, wA, HDIM, HDIM, attn_b + (size_t)l * NBLK * HDIM, idx, k, HDIM,
          scalev + k * HDIM, x, nullptr, 1.0f);
      ln_kernel<<<MTOT, 256, 0, stream>>>(x, g2 + (size_t)l * NBLK * HDIM,
                                          b2 + (size_t)l * NBLK * HDIM, idx, k,
                                          abf);
      gemm_layer<64, 64, 1><<<dim3(8, 64), 256, 0, stream>>>(
          abf, w1, HFF, HDIM, ff1_b + (size_t)l * NBLK * HFF, idx, k, HFF,
          nullptr, nullptr, tbuf, 1.0f);
      float lsc = (k == 1) ? 1.5f : 1.0f;
      gemm_layer<128, 64, 2><<<dim3(16, 32), 256, 0, stream>>>(
          tbuf, w2, HDIM, HFF, ff2_b + (size_t)l * NBLK * HDIM, idx, k, HDIM,
          nullptr, x, nullptr, lsc);
    }
  }

  gemm_lm<<<2000, 512, 0, stream>>>(x, lmT, lm_b, out);
}

// Round 19
// 923.842 us; speedup vs baseline: 1.1380x; 1.0162x over previous
//
#include <hip/hip_runtime.h>

// ---------------------------------------------------------------------------
// UltimateTNN: MoE-ish transformer forward on MI355X (gfx950).
// B=8 S=512 H=1024 HF=512 V=32000 L=4 NB=8 K=2, M = B*S = 4096.
// Round 19: attn & ff2 layer GEMMs -> 64x64 tiles (grid 1024 = 4 blocks/CU;
// occupancy was grid-capped at 2). A/W are L3-resident so no FETCH blowup
// (unlike round-17's LM case). Everything else = round-18 best state.
// ---------------------------------------------------------------------------

typedef unsigned short u16;
typedef short bf16x8 __attribute__((ext_vector_type(8)));
typedef float f32x4 __attribute__((ext_vector_type(4)));

struct __align__(8) u16x4_t { u16 x, y, z, w; };

#define MTOT 4096
#define HDIM 1024
#define HFF  512
#define VOC  32000
#define NLAYER 4
#define NBLK 8

#define VMW(n) asm volatile("s_waitcnt vmcnt(" #n ")" ::: "memory")
#define BARR() do { asm volatile("" ::: "memory"); __builtin_amdgcn_s_barrier(); asm volatile("" ::: "memory"); } while (0)

__device__ __forceinline__ u16 f2bf(float f) {
  unsigned u = __float_as_uint(f);
  unsigned r = u + 0x7FFFu + ((u >> 16) & 1u);
  return (u16)(r >> 16);
}

__device__ __forceinline__ float b2f(u16 v) {
  return __uint_as_float(((unsigned)v) << 16);
}

__device__ __forceinline__ float sigmoidf_(float z) {
  return 1.0f / (1.0f + expf(-z));
}

__device__ __forceinline__ void gload16(const void* g, void* l) {
  __builtin_amdgcn_global_load_lds(
      (const __attribute__((address_space(1))) void*)g,
      (__attribute__((address_space(3))) void*)l, 16, 0, 0);
}

// ---------------- embed + lm_w transpose (merged, independent) --------------
__global__ void embed_lm_kernel(const int* __restrict__ ids,
                                const float* __restrict__ emb,
                                const float* __restrict__ pos,
                                u16* __restrict__ x,
                                const float* __restrict__ lm_w,
                                u16* __restrict__ lmT) {
  __shared__ float tile[32][33];
  int b = blockIdx.x, tid = threadIdx.x;
  if (b < MTOT) {
    int s = b & 511;
    int id = ids[b];
    float4 e = ((const float4*)(emb + (size_t)id * HDIM))[tid];
    float4 p = ((const float4*)(pos + (size_t)s * HDIM))[tid];
    u16x4_t r;
    r.x = f2bf(e.x + p.x); r.y = f2bf(e.y + p.y);
    r.z = f2bf(e.z + p.z); r.w = f2bf(e.w + p.w);
    ((u16x4_t*)(x + (size_t)b * HDIM))[tid] = r;
    return;
  }
  int c = b - MTOT;                 // 0..31999
  int n0 = (c % 1000) * 32, k0 = (c / 1000) * 32;
  int tx = tid & 31, ty = tid >> 5; // (32,8)
#pragma unroll
  for (int j = 0; j < 4; ++j) {
    int kr = k0 + ty + j * 8;
    tile[ty + j * 8][tx] = lm_w[(size_t)kr * VOC + n0 + tx];
  }
  __syncthreads();
#pragma unroll
  for (int j = 0; j < 4; ++j) {
    int nr = n0 + ty + j * 8;
    lmT[(size_t)nr * HDIM + k0 + tx] = f2bf(tile[tx][ty + j * 8]);
  }
}

// --------------------------- router ----------------------------------------
__global__ void colsum_kernel(const u16* __restrict__ x, float* __restrict__ partial) {
  int j = blockIdx.x;            // 0..63
  int t = threadIdx.x;           // 0..255 (4 elems each)
  float4 s; s.x = 0.f; s.y = 0.f; s.z = 0.f; s.w = 0.f;
  for (int r = 0; r < 8; ++r) {
    u16x4_t a = ((const u16x4_t*)(x + (size_t)(j * 8 + r) * HDIM))[t];
    s.x += b2f(a.x); s.y += b2f(a.y); s.z += b2f(a.z); s.w += b2f(a.w);
  }
  ((float4*)(partial + (size_t)j * HDIM))[t] = s;
}

__global__ void router_finalize(const float* __restrict__ partial,
                                const float* __restrict__ selw,   // [H][NB]
                                const float* __restrict__ selb,   // [NB]
                                const float* __restrict__ tg_l,   // [NB][H]
                                const float* __restrict__ tf,     // [H]
                                int* __restrict__ idx_out,        // [2]
                                float* __restrict__ scale_out) {  // [2][H]
  int t = threadIdx.x;           // 0..1023
  float s = 0.f;
  for (int j = 0; j < 64; ++j) s += partial[(size_t)j * HDIM + t];
  float mean = s * (1.0f / 512.0f);
  __shared__ float sm[HDIM];
  __shared__ float sc[NBLK];
  __shared__ int sidx[2];
  sm[t] = mean;
  __syncthreads();
  int wave = t >> 6, lane = t & 63;
  if (wave < NBLK) {
    float p = 0.f;
    for (int h = lane; h < HDIM; h += 64) p += sm[h] * selw[h * NBLK + wave];
    for (int o = 32; o; o >>= 1) p += __shfl_down(p, o);
    if (lane == 0) sc[wave] = p;
  }
  __syncthreads();
  if (t == 0) {
    float adj[NBLK];
    for (int i = 0; i < NBLK; ++i) {
      float z = sc[i] + selb[i];
      adj[i] = sigmoidf_(z) * 0.7f + 0.15f;   // PRIORITY=0.5 * 0.3
    }
    int i0 = 0;
    for (int i = 1; i < NBLK; ++i) if (adj[i] > adj[i0]) i0 = i;
    int i1 = -1;
    for (int i = 0; i < NBLK; ++i) {
      if (i == i0) continue;
      if (i1 < 0 || adj[i] > adj[i1]) i1 = i;
    }
    idx_out[0] = i0; idx_out[1] = i1;
    sidx[0] = i0; sidx[1] = i1;
  }
  __syncthreads();
  for (int k = 0; k < 2; ++k) {
    int id = sidx[k];
    float z = tg_l[(size_t)id * HDIM + t];
    scale_out[k * HDIM + t] = 1.0f + sigmoidf_(z) * tf[t];
  }
}

// --------- prep: weight transpose (slot k) + LN1 (slot k), one launch ------
__global__ void prep_kernel(const float* __restrict__ aw,
                            const float* __restrict__ f1w,
                            const float* __restrict__ f2w,
                            const int* __restrict__ idx, int slot,
                            u16* __restrict__ wA, u16* __restrict__ w1,
                            u16* __restrict__ w2,
                            const u16* __restrict__ x,
                            const float* __restrict__ g_base,
                            const float* __restrict__ b_base,
                            u16* __restrict__ abf) {
  __shared__ float sh[32 * 33];
  int b = blockIdx.x, tid = threadIdx.x;
  int id = idx[slot];
  if (b < 2048) {
    float (*tile)[33] = (float(*)[33])sh;
    const float* src; u16* dst; int K, N, n0, k0;
    if (b < 1024) {
      K = 1024; N = 1024; src = aw + (size_t)id * 1024 * 1024;
      n0 = (b & 31) * 32; k0 = (b >> 5) * 32; dst = wA;
    } else if (b < 1536) {
      int c = b - 1024; K = 1024; N = 512; src = f1w + (size_t)id * 1024 * 512;
      n0 = (c & 15) * 32; k0 = (c >> 4) * 32; dst = w1;
    } else {
      int c = b - 1536; K = 512; N = 1024; src = f2w + (size_t)id * 512 * 1024;
      n0 = (c & 31) * 32; k0 = (c >> 5) * 32; dst = w2;
    }
    int tx = tid & 31, ty = tid >> 5;
#pragma unroll
    for (int j = 0; j < 4; ++j) {
      int kr = k0 + ty + j * 8;
      tile[ty + j * 8][tx] = src[(size_t)kr * N + n0 + tx];
    }
    __syncthreads();
#pragma unroll
    for (int j = 0; j < 4; ++j) {
      int nr = n0 + ty + j * 8;
      dst[(size_t)nr * K + k0 + tx] = f2bf(tile[tx][ty + j * 8]);
    }
    return;
  }
  // ---- LN1 ----
  int row = b - 2048, t = tid;
  const float* g = g_base + (size_t)id * HDIM;
  const float* bb = b_base + (size_t)id * HDIM;
  u16x4_t xv = ((const u16x4_t*)(x + (size_t)row * HDIM))[t];
  float v0 = b2f(xv.x), v1 = b2f(xv.y), v2 = b2f(xv.z), v3 = b2f(xv.w);
  float s = v0 + v1 + v2 + v3;
  float q = v0 * v0 + v1 * v1 + v2 * v2 + v3 * v3;
  for (int o = 32; o; o >>= 1) { s += __shfl_down(s, o); q += __shfl_down(q, o); }
  float* ss = sh; float* sq = sh + 8;
  int wave = t >> 6, lane = t & 63;
  if (lane == 0) { ss[wave] = s; sq[wave] = q; }
  __syncthreads();
  if (t == 0) {
    float S = ss[0] + ss[1] + ss[2] + ss[3];
    float Q = sq[0] + sq[1] + sq[2] + sq[3];
    ss[0] = S * (1.0f / 1024.0f);
    sq[0] = Q * (1.0f / 1024.0f);
  }
  __syncthreads();
  float mean = ss[0];
  float var = sq[0] - mean * mean;
  float rs = rsqrtf(var + 1e-5f);
  float4 gv = ((const float4*)g)[t];
  float4 bv = ((const float4*)bb)[t];
  u16x4_t o4;
  o4.x = f2bf((v0 - mean) * rs * gv.x + bv.x);
  o4.y = f2bf((v1 - mean) * rs * gv.y + bv.y);
  o4.z = f2bf((v2 - mean) * rs * gv.z + bv.z);
  o4.w = f2bf((v3 - mean) * rs * gv.w + bv.w);
  ((u16x4_t*)(abf + (size_t)row * HDIM))[t] = o4;
}

// --------------------------- layernorm -> bf16 (ln2) ------------------------
__global__ void ln_kernel(const u16* __restrict__ x,
                          const float* __restrict__ g_base,
                          const float* __restrict__ b_base,
                          const int* __restrict__ idx_ptr, int slot,
                          u16* __restrict__ out) {
  int row = blockIdx.x, t = threadIdx.x;     // 256 threads, 4 elems each
  size_t off = (size_t)idx_ptr[slot] * HDIM;
  const float* g = g_base + off;
  const float* b = b_base + off;
  u16x4_t xv = ((const u16x4_t*)(x + (size_t)row * HDIM))[t];
  float v0 = b2f(xv.x), v1 = b2f(xv.y), v2 = b2f(xv.z), v3 = b2f(xv.w);
  float s = v0 + v1 + v2 + v3;
  float q = v0 * v0 + v1 * v1 + v2 * v2 + v3 * v3;
  for (int o = 32; o; o >>= 1) { s += __shfl_down(s, o); q += __shfl_down(q, o); }
  __shared__ float ss[4], sq[4];
  int wave = t >> 6, lane = t & 63;
  if (lane == 0) { ss[wave] = s; sq[wave] = q; }
  __syncthreads();
  if (t == 0) {
    float S = ss[0] + ss[1] + ss[2] + ss[3];
    float Q = sq[0] + sq[1] + sq[2] + sq[3];
    ss[0] = S * (1.0f / 1024.0f);
    sq[0] = Q * (1.0f / 1024.0f);
  }
  __syncthreads();
  float mean = ss[0];
  float var = sq[0] - mean * mean;
  float rs = rsqrtf(var + 1e-5f);
  float4 gv = ((const float4*)g)[t];
  float4 bv = ((const float4*)b)[t];
  u16x4_t o4;
  o4.x = f2bf((v0 - mean) * rs * gv.x + bv.x);
  o4.y = f2bf((v1 - mean) * rs * gv.y + bv.y);
  o4.z = f2bf((v2 - mean) * rs * gv.z + bv.z);
  o4.w = f2bf((v3 - mean) * rs * gv.w + bv.w);
  ((u16x4_t*)(out + (size_t)row * HDIM))[t] = o4;
}

// --------------------------- layer GEMM (BK=128) ----------------------------
// C[M=4096][N] = A[M][K](bf16) * Bt[N][K](bf16)^T, fp32 acc, fused epilogues.
// BK=128, 256 threads = 4 waves (2Mx2N), 16B-group XOR swizzle. Row-major
// epilogue. Residual x is bf16 (fp32 math in-register).
// EPI 0: x = bf16(x + 0.5*(c+bias)*scale)       (attn; N==H)
// EPI 1: outb = bf16(gelu(c+bias))              (ff1)
// EPI 2: x = bf16((x + 0.5*(c+bias)) * lscale)  (ff2)
template <int BM, int BN, int EPI>
__global__ __launch_bounds__(256) void gemm_layer(
    const u16* __restrict__ A, const u16* __restrict__ Bt, int N, int K,
    const float* __restrict__ bias_base, const int* __restrict__ idx_ptr,
    int slot, int bias_stride, const float* __restrict__ scale,
    u16* __restrict__ xres, u16* __restrict__ outb, float lscale) {
  constexpr int TM = BM / 2, TN = BN / 2;
  constexpr int FM = TM / 16, FN = TN / 16;
  constexpr int NLD = (BM + BN) / 16;       // gloads/thread/step (BK=128)
  __shared__ __align__(16) u16 lds[(BM + BN) * 128];

  const int tid = threadIdx.x, wave = tid >> 6, lane = tid & 63;
  const int m0 = blockIdx.y * BM, n0 = blockIdx.x * BN;
  const int wm = wave >> 1, wn = wave & 1;
  const int fr = lane & 15, g = lane >> 4;
  const float* bias =
      bias_base + (idx_ptr ? (size_t)idx_ptr[slot] * bias_stride : 0);

  const u16* gbase[NLD];
  unsigned ldsoff[NLD];
#pragma unroll
  for (int j = 0; j < NLD; ++j) {
    int lo = (tid + j * 256) * 16;        // byte offset in (BM+BN)*256 tile
    int q = (lo >> 4) & 15;               // 16B-group within 256B row
    if (lo < BM * 256) {
      int row = lo >> 8;
      gbase[j] = A + (size_t)(m0 + row) * K + (q ^ (row & 7)) * 8;
    } else {
      int bo = lo - BM * 256;
      int row = bo >> 8;
      gbase[j] = Bt + (size_t)(n0 + row) * K + (q ^ (row & 7)) * 8;
    }
    ldsoff[j] = (unsigned)(lo >> 1);
  }

  unsigned offA[FM][4], offB[FN][4];
#pragma unroll
  for (int mi = 0; mi < FM; ++mi)
#pragma unroll
    for (int kk = 0; kk < 4; ++kk)
      offA[mi][kk] = (unsigned)((wm * TM + mi * 16 + fr) * 256 +
                                (((kk * 4 + g) ^ (fr & 7)) << 4));
#pragma unroll
  for (int ni = 0; ni < FN; ++ni)
#pragma unroll
    for (int kk = 0; kk < 4; ++kk)
      offB[ni][kk] = (unsigned)(BM * 256 + (wn * TN + ni * 16 + fr) * 256 +
                                (((kk * 4 + g) ^ (fr & 7)) << 4));

  f32x4 acc[FM][FN];
#pragma unroll
  for (int i = 0; i < FM; ++i)
#pragma unroll
    for (int j = 0; j < FN; ++j) acc[i][j] = (f32x4){0.f, 0.f, 0.f, 0.f};

  for (int kt = 0; kt < K; kt += 128) {
#pragma unroll
    for (int j = 0; j < NLD; ++j) gload16(gbase[j] + kt, lds + ldsoff[j]);
    __syncthreads();
#pragma unroll
    for (int kk = 0; kk < 4; ++kk) {
      bf16x8 af[FM], bf[FN];
#pragma unroll
      for (int mi = 0; mi < FM; ++mi)
        af[mi] = *(const bf16x8*)((const char*)lds + offA[mi][kk]);
#pragma unroll
      for (int ni = 0; ni < FN; ++ni)
        bf[ni] = *(const bf16x8*)((const char*)lds + offB[ni][kk]);
#pragma unroll
      for (int mi = 0; mi < FM; ++mi)
#pragma unroll
        for (int ni = 0; ni < FN; ++ni)
          acc[mi][ni] = __builtin_amdgcn_mfma_f32_16x16x32_bf16(
              af[mi], bf[ni], acc[mi][ni], 0, 0, 0);
    }
    __syncthreads();
  }

  // ---- epilogue: row-major order, ni innermost ----
  const int rb = g * 4, cn = fr;
  float bvv[FN], svv[FN];
#pragma unroll
  for (int ni = 0; ni < FN; ++ni) {
    int n = n0 + wn * TN + ni * 16 + cn;
    bvv[ni] = bias[n];
    svv[ni] = (EPI == 0) ? scale[n] : 0.f;
  }
#pragma unroll
  for (int mi = 0; mi < FM; ++mi) {
#pragma unroll
    for (int r = 0; r < 4; ++r) {
      int m = m0 + wm * TM + mi * 16 + rb + r;
      size_t base = (size_t)m * N + n0 + wn * TN + cn;
#pragma unroll
      for (int ni = 0; ni < FN; ++ni) {
        float c = acc[mi][ni][r] + bvv[ni];
        size_t o = base + ni * 16;
        if (EPI == 0) {
          float xv = b2f(xres[o]);
          xres[o] = f2bf(xv + 0.5f * (c * svv[ni]));
        } else if (EPI == 1) {
          float ge = 0.5f * c * (1.0f + erff(c * 0.70710678118654752f));
          outb[o] = f2bf(ge);
        } else {
          float xv = b2f(xres[o]);
          xres[o] = f2bf((xv + 0.5f * c) * lscale);
        }
      }
    }
  }
}

// --------------------------- LM-head GEMM (round-12 best) -------------------
// out[4096][32000] = x[4096][1024](bf16) @ lmT[32000][1024](bf16)^T + bias.
// 256x256 tile, 8 waves 2Mx4N. BK=64, double-buffered, 4 phases; units
// aligned to phase reads; VMW(2)+BARR at P1/P2 only. Swizzle, XCD chunking,
// row-major NT epilogue. Closed at measured plateau (~315 us, 7 variants).
__global__ __launch_bounds__(512, 2) void gemm_lm(
    const u16* __restrict__ A, const u16* __restrict__ Bt,
    const float* __restrict__ bias, float* __restrict__ out) {
  constexpr int K = HDIM;      // 1024
  constexpr int N = VOC;       // 32000
  constexpr int NT = K / 64;   // 16 K-tiles
  __shared__ __align__(16) u16 smbuf[2 * 32768];   // 2 x 64 KB

  const int tid = threadIdx.x, wid = tid >> 6, lane = tid & 63;
  const int bid = blockIdx.x;
  const int vbid = (bid & 7) * 250 + (bid >> 3);
  const int n0 = (vbid >> 4) * 256;
  const int m0 = (vbid & 15) * 256;
  const int wm = wid >> 2, wn = wid & 3;   // 2 x 4 waves
  const int fr = lane & 15, g = lane >> 4;

  const int r0 = tid >> 3, q = tid & 7;
  const int sg = (q ^ (r0 & 7)) * 8;         // u16 offset of swizzled group
  const u16* usrc[4][2];
  unsigned uoff[4][2];                       // u16 offsets within a buffer
  usrc[0][0] = Bt + (size_t)(n0 + r0) * K + sg;        uoff[0][0] = 16384u + tid * 8;
  usrc[0][1] = Bt + (size_t)(n0 + 64 + r0) * K + sg;   uoff[0][1] = 20480u + tid * 8;
  usrc[1][0] = Bt + (size_t)(n0 + 128 + r0) * K + sg;  uoff[1][0] = 24576u + tid * 8;
  usrc[1][1] = Bt + (size_t)(n0 + 192 + r0) * K + sg;  uoff[1][1] = 28672u + tid * 8;
  usrc[2][0] = A + (size_t)(m0 + r0) * K + sg;         uoff[2][0] = 0u + tid * 8;
  usrc[2][1] = A + (size_t)(m0 + 128 + r0) * K + sg;   uoff[2][1] = 8192u + tid * 8;
  usrc[3][0] = A + (size_t)(m0 + 64 + r0) * K + sg;    uoff[3][0] = 4096u + tid * 8;
  usrc[3][1] = A + (size_t)(m0 + 192 + r0) * K + sg;   uoff[3][1] = 12288u + tid * 8;

  unsigned offA[8][2], offB[4][2];
#pragma unroll
  for (int mi = 0; mi < 8; ++mi)
#pragma unroll
    for (int kk = 0; kk < 2; ++kk)
      offA[mi][kk] = (unsigned)((wm * 128 + mi * 16 + fr) * 128 +
                                (((kk * 4 + g) ^ (fr & 7)) << 4));
#pragma unroll
  for (int ni = 0; ni < 4; ++ni)
#pragma unroll
    for (int kk = 0; kk < 2; ++kk)
      offB[ni][kk] = (unsigned)(32768 + (wn * 64 + ni * 16 + fr) * 128 +
                                (((kk * 4 + g) ^ (fr & 7)) << 4));

  f32x4 acc[8][4];
#pragma unroll
  for (int i = 0; i < 8; ++i)
#pragma unroll
    for (int j = 0; j < 4; ++j) acc[i][j] = (f32x4){0.f, 0.f, 0.f, 0.f};

  // prologue: stage tile 0 into buf0 in ledger order u0,u1,u2,u3
#pragma unroll
  for (int u = 0; u < 4; ++u) {
    gload16(usrc[u][0], smbuf + uoff[u][0]);
    gload16(usrc[u][1], smbuf + uoff[u][1]);
  }

  for (int t = 0; t < NT; ++t) {
    const char* cb = (const char*)smbuf + (size_t)(t & 1) * 65536;
    u16* nb = smbuf + ((t + 1) & 1) * 32768;
    const int ko = (t + 1) * 64;
    const bool st = (t + 1 < NT);
    bf16x8 avl[4], avh[4], bv[4];
    // ---- P1: kk0, mi0-3 ---- needs u0,u1,u2 of tile t (VMW(2) leaves u3)
    VMW(2);
    BARR();
#pragma unroll
    for (int ni = 0; ni < 4; ++ni) bv[ni] = *(const bf16x8*)(cb + offB[ni][0]);
#pragma unroll
    for (int mi = 0; mi < 4; ++mi) avl[mi] = *(const bf16x8*)(cb + offA[mi][0]);
    if (st) {
      gload16(usrc[0][0] + ko, nb + uoff[0][0]);
      gload16(usrc[0][1] + ko, nb + uoff[0][1]);
    }
    __builtin_amdgcn_s_setprio(1);
#pragma unroll
    for (int mi = 0; mi < 4; ++mi)
#pragma unroll
      for (int ni = 0; ni < 4; ++ni)
        acc[mi][ni] = __builtin_amdgcn_mfma_f32_16x16x32_bf16(
            avl[mi], bv[ni], acc[mi][ni], 0, 0, 0);
    __builtin_amdgcn_s_setprio(0);
    // ---- P2: kk0, mi4-7 ---- needs u3 of tile t
    if (t < NT - 1) { VMW(2); } else { VMW(0); }
    BARR();
#pragma unroll
    for (int mi = 0; mi < 4; ++mi)
      avh[mi] = *(const bf16x8*)(cb + offA[4 + mi][0]);
    if (st) {
      gload16(usrc[1][0] + ko, nb + uoff[1][0]);
      gload16(usrc[1][1] + ko, nb + uoff[1][1]);
    }
    __builtin_amdgcn_s_setprio(1);
#pragma unroll
    for (int mi = 0; mi < 4; ++mi)
#pragma unroll
      for (int ni = 0; ni < 4; ++ni)
        acc[4 + mi][ni] = __builtin_amdgcn_mfma_f32_16x16x32_bf16(
            avh[mi], bv[ni], acc[4 + mi][ni], 0, 0, 0);
    __builtin_amdgcn_s_setprio(0);
    // ---- P3: kk1, mi0-3 ---- (resident)
#pragma unroll
    for (int ni = 0; ni < 4; ++ni) bv[ni] = *(const bf16x8*)(cb + offB[ni][1]);
#pragma unroll
    for (int mi = 0; mi < 4; ++mi) avl[mi] = *(const bf16x8*)(cb + offA[mi][1]);
    if (st) {
      gload16(usrc[2][0] + ko, nb + uoff[2][0]);
      gload16(usrc[2][1] + ko, nb + uoff[2][1]);
    }
    __builtin_amdgcn_s_setprio(1);
#pragma unroll
    for (int mi = 0; mi < 4; ++mi)
#pragma unroll
      for (int ni = 0; ni < 4; ++ni)
        acc[mi][ni] = __builtin_amdgcn_mfma_f32_16x16x32_bf16(
            avl[mi], bv[ni], acc[mi][ni], 0, 0, 0);
    __builtin_amdgcn_s_setprio(0);
    // ---- P4: kk1, mi4-7 ----
#pragma unroll
    for (int mi = 0; mi < 4; ++mi)
      avh[mi] = *(const bf16x8*)(cb + offA[4 + mi][1]);
    if (st) {
      gload16(usrc[3][0] + ko, nb + uoff[3][0]);
      gload16(usrc[3][1] + ko, nb + uoff[3][1]);
    }
    __builtin_amdgcn_s_setprio(1);
#pragma unroll
    for (int mi = 0; mi < 4; ++mi)
#pragma unroll
      for (int ni = 0; ni < 4; ++ni)
        acc[4 + mi][ni] = __builtin_amdgcn_mfma_f32_16x16x32_bf16(
            avh[mi], bv[ni], acc[4 + mi][ni], 0, 0, 0);
    __builtin_amdgcn_s_setprio(0);
  }

  // ---- epilogue: row-major, ni innermost -> 4 consecutive 64B chunks ------
  const int rb = g * 4, cn = fr;
  float bvv[4];
#pragma unroll
  for (int ni = 0; ni < 4; ++ni) bvv[ni] = bias[n0 + wn * 64 + ni * 16 + cn];
#pragma unroll
  for (int mi = 0; mi < 8; ++mi) {
#pragma unroll
    for (int r = 0; r < 4; ++r) {
      int m = m0 + wm * 128 + mi * 16 + rb + r;
      float* orow = out + (size_t)m * N + n0 + wn * 64 + cn;
#pragma unroll
      for (int ni = 0; ni < 4; ++ni)
        __builtin_nontemporal_store(acc[mi][ni][r] + bvv[ni], orow + ni * 16);
    }
  }
}

// --------------------------- launch ----------------------------------------
extern "C" void kernel_launch(void* const* d_in, const int* in_sizes, int n_in,
                              void* d_out, int out_size, void* d_ws,
                              size_t ws_size, hipStream_t stream) {
  (void)in_sizes; (void)n_in; (void)out_size; (void)ws_size;
  const int*   ids    = (const int*)d_in[0];
  const float* emb    = (const float*)d_in[1];
  const float* pos    = (const float*)d_in[2];
  const float* tf     = (const float*)d_in[3];
  const float* lm_w   = (const float*)d_in[4];
  const float* lm_b   = (const float*)d_in[5];
  const float* sel_w  = (const float*)d_in[6];
  const float* sel_b  = (const float*)d_in[7];
  const float* g1     = (const float*)d_in[8];
  const float* b1     = (const float*)d_in[9];
  const float* attn_w = (const float*)d_in[10];
  const float* attn_b = (const float*)d_in[11];
  const float* g2     = (const float*)d_in[12];
  const float* b2     = (const float*)d_in[13];
  const float* ff1_w  = (const float*)d_in[14];
  const float* ff1_b  = (const float*)d_in[15];
  const float* ff2_w  = (const float*)d_in[16];
  const float* ff2_b  = (const float*)d_in[17];
  const float* tg     = (const float*)d_in[18];
  float* out = (float*)d_out;

  char* ws = (char*)d_ws;
  u16*   x       = (u16*)(ws + 0);            // 8 MB bf16 residual
  u16*   abf     = (u16*)(ws + 16777216);     // 8 MB bf16 LN out
  u16*   tbuf    = (u16*)(ws + 25165824);     // 4 MB bf16 gelu out
  u16*   wA      = (u16*)(ws + 29360128);     // 2 MB attn W^T
  u16*   w1      = (u16*)(ws + 31457280);     // 1 MB ff1 W^T
  u16*   w2      = (u16*)(ws + 32505856);     // 1 MB ff2 W^T
  u16*   lmT     = (u16*)(ws + 33554432);     // 62.5 MB lm W^T
  float* partial = (float*)(ws + 99090432);   // 256 KB router colsum
  float* scalev  = (float*)(ws + 99352576);   // 8 KB torsion scales
  int*   idx     = (int*)(ws + 99360768);     // 8 B top-2 indices

  embed_lm_kernel<<<MTOT + VOC, 256, 0, stream>>>(ids, emb, pos, x, lm_w, lmT);

  for (int l = 0; l < NLAYER; ++l) {
    colsum_kernel<<<64, 256, 0, stream>>>(x, partial);
    router_finalize<<<1, 1024, 0, stream>>>(
        partial, sel_w + (size_t)l * HDIM * NBLK, sel_b + l * NBLK,
        tg + (size_t)l * NBLK * HDIM, tf, idx, scalev);
    const float* aw_l  = attn_w + (size_t)l * NBLK * HDIM * HDIM;
    const float* f1w_l = ff1_w + (size_t)l * NBLK * HDIM * HFF;
    const float* f2w_l = ff2_w + (size_t)l * NBLK * HFF * HDIM;
    for (int k = 0; k < 2; ++k) {
      prep_kernel<<<2048 + MTOT, 256, 0, stream>>>(
          aw_l, f1w_l, f2w_l, idx, k, wA, w1, w2, x,
          g1 + (size_t)l * NBLK * HDIM, b1 + (size_t)l * NBLK * HDIM, abf);
      // attn: 64x64 tile, grid (16, 64) = 1024 blocks = 4 blocks/CU
      gemm_layer<64, 64, 0><<<dim3(16, 64), 256, 0, stream>>>(
          abf, wA, HDIM, HDIM, attn_b + (size_t)l * NBLK * HDIM, idx, k, HDIM,
          scalev + k * HDIM, x, nullptr, 1.0f);
      ln_kernel<<<MTOT, 256, 0, stream>>>(x, g2 + (size_t)l * NBLK * HDIM,
                                          b2 + (size_t)l * NBLK * HDIM, idx, k,
                                          abf);
      // ff1: 64x64 tile, grid (8, 64) = 512 blocks
      gemm_layer<64, 64, 1><<<dim3(8, 64), 256, 0, stream>>>(
          abf, w1, HFF, HDIM, ff1_b + (size_t)l * NBLK * HFF, idx, k, HFF,
          nullptr, nullptr, tbuf, 1.0f);
      float lsc = (k == 1) ? 1.5f : 1.0f;
      // ff2: 64x64 tile, grid (16, 64) = 1024 blocks = 4 blocks/CU
      gemm_layer<64, 64, 2><<<dim3(16, 64), 256, 0, stream>>>(
          tbuf, w2, HDIM, HFF, ff2_b + (size_t)l * NBLK * HDIM, idx, k, HDIM,
          nullptr, x, nullptr, lsc);
    }
  }

  gemm_lm<<<2000, 512, 0, stream>>>(x, lmT, lm_b, out);
}

// Round 20
// 920.994 us; speedup vs baseline: 1.1415x; 1.0031x over previous
//
#include <hip/hip_runtime.h>

// ---------------------------------------------------------------------------
// UltimateTNN: MoE-ish transformer forward on MI355X (gfx950).
// B=8 S=512 H=1024 HF=512 V=32000 L=4 NB=8 K=2, M = B*S = 4096.
// Round 20: both experts' weight transposes hoisted into the k=0 prep launch
// (transpose depends only on idx, not x); k=1 prep collapses to LN1-only.
// k-indexed weight buffers in the 8 MB gap freed by bf16 x. Everything else
// = round-19 best (923.8 us): bf16 residual, 64^2 attn/ff2, BK=128 layers,
// 256^2 4-phase gemm_lm (closed plateau ~318 us).
// ---------------------------------------------------------------------------

typedef unsigned short u16;
typedef short bf16x8 __attribute__((ext_vector_type(8)));
typedef float f32x4 __attribute__((ext_vector_type(4)));

struct __align__(8) u16x4_t { u16 x, y, z, w; };

#define MTOT 4096
#define HDIM 1024
#define HFF  512
#define VOC  32000
#define NLAYER 4
#define NBLK 8

#define VMW(n) asm volatile("s_waitcnt vmcnt(" #n ")" ::: "memory")
#define BARR() do { asm volatile("" ::: "memory"); __builtin_amdgcn_s_barrier(); asm volatile("" ::: "memory"); } while (0)

__device__ __forceinline__ u16 f2bf(float f) {
  unsigned u = __float_as_uint(f);
  unsigned r = u + 0x7FFFu + ((u >> 16) & 1u);
  return (u16)(r >> 16);
}

__device__ __forceinline__ float b2f(u16 v) {
  return __uint_as_float(((unsigned)v) << 16);
}

__device__ __forceinline__ float sigmoidf_(float z) {
  return 1.0f / (1.0f + expf(-z));
}

__device__ __forceinline__ void gload16(const void* g, void* l) {
  __builtin_amdgcn_global_load_lds(
      (const __attribute__((address_space(1))) void*)g,
      (__attribute__((address_space(3))) void*)l, 16, 0, 0);
}

// ---------------- embed + lm_w transpose (merged, independent) --------------
__global__ void embed_lm_kernel(const int* __restrict__ ids,
                                const float* __restrict__ emb,
                                const float* __restrict__ pos,
                                u16* __restrict__ x,
                                const float* __restrict__ lm_w,
                                u16* __restrict__ lmT) {
  __shared__ float tile[32][33];
  int b = blockIdx.x, tid = threadIdx.x;
  if (b < MTOT) {
    int s = b & 511;
    int id = ids[b];
    float4 e = ((const float4*)(emb + (size_t)id * HDIM))[tid];
    float4 p = ((const float4*)(pos + (size_t)s * HDIM))[tid];
    u16x4_t r;
    r.x = f2bf(e.x + p.x); r.y = f2bf(e.y + p.y);
    r.z = f2bf(e.z + p.z); r.w = f2bf(e.w + p.w);
    ((u16x4_t*)(x + (size_t)b * HDIM))[tid] = r;
    return;
  }
  int c = b - MTOT;                 // 0..31999
  int n0 = (c % 1000) * 32, k0 = (c / 1000) * 32;
  int tx = tid & 31, ty = tid >> 5; // (32,8)
#pragma unroll
  for (int j = 0; j < 4; ++j) {
    int kr = k0 + ty + j * 8;
    tile[ty + j * 8][tx] = lm_w[(size_t)kr * VOC + n0 + tx];
  }
  __syncthreads();
#pragma unroll
  for (int j = 0; j < 4; ++j) {
    int nr = n0 + ty + j * 8;
    lmT[(size_t)nr * HDIM + k0 + tx] = f2bf(tile[tx][ty + j * 8]);
  }
}

// --------------------------- router ----------------------------------------
__global__ void colsum_kernel(const u16* __restrict__ x, float* __restrict__ partial) {
  int j = blockIdx.x;            // 0..63
  int t = threadIdx.x;           // 0..255 (4 elems each)
  float4 s; s.x = 0.f; s.y = 0.f; s.z = 0.f; s.w = 0.f;
  for (int r = 0; r < 8; ++r) {
    u16x4_t a = ((const u16x4_t*)(x + (size_t)(j * 8 + r) * HDIM))[t];
    s.x += b2f(a.x); s.y += b2f(a.y); s.z += b2f(a.z); s.w += b2f(a.w);
  }
  ((float4*)(partial + (size_t)j * HDIM))[t] = s;
}

__global__ void router_finalize(const float* __restrict__ partial,
                                const float* __restrict__ selw,   // [H][NB]
                                const float* __restrict__ selb,   // [NB]
                                const float* __restrict__ tg_l,   // [NB][H]
                                const float* __restrict__ tf,     // [H]
                                int* __restrict__ idx_out,        // [2]
                                float* __restrict__ scale_out) {  // [2][H]
  int t = threadIdx.x;           // 0..1023
  float s = 0.f;
  for (int j = 0; j < 64; ++j) s += partial[(size_t)j * HDIM + t];
  float mean = s * (1.0f / 512.0f);
  __shared__ float sm[HDIM];
  __shared__ float sc[NBLK];
  __shared__ int sidx[2];
  sm[t] = mean;
  __syncthreads();
  int wave = t >> 6, lane = t & 63;
  if (wave < NBLK) {
    float p = 0.f;
    for (int h = lane; h < HDIM; h += 64) p += sm[h] * selw[h * NBLK + wave];
    for (int o = 32; o; o >>= 1) p += __shfl_down(p, o);
    if (lane == 0) sc[wave] = p;
  }
  __syncthreads();
  if (t == 0) {
    float adj[NBLK];
    for (int i = 0; i < NBLK; ++i) {
      float z = sc[i] + selb[i];
      adj[i] = sigmoidf_(z) * 0.7f + 0.15f;   // PRIORITY=0.5 * 0.3
    }
    int i0 = 0;
    for (int i = 1; i < NBLK; ++i) if (adj[i] > adj[i0]) i0 = i;
    int i1 = -1;
    for (int i = 0; i < NBLK; ++i) {
      if (i == i0) continue;
      if (i1 < 0 || adj[i] > adj[i1]) i1 = i;
    }
    idx_out[0] = i0; idx_out[1] = i1;
    sidx[0] = i0; sidx[1] = i1;
  }
  __syncthreads();
  for (int k = 0; k < 2; ++k) {
    int id = sidx[k];
    float z = tg_l[(size_t)id * HDIM + t];
    scale_out[k * HDIM + t] = 1.0f + sigmoidf_(z) * tf[t];
  }
}

// --- prep_both: BOTH experts' weight transposes + LN1(k=0), one launch -----
// blocks [0,4096): transpose; kk = b>>11, c = b&2047:
//   c<1024 attn 32x32 tile; c<1536 ff1; else ff2. dst indexed by kk.
// blocks [4096,8192): LN1 of row (b-4096) with idx[0] -> abf.
__global__ void prep_both(const float* __restrict__ aw,
                          const float* __restrict__ f1w,
                          const float* __restrict__ f2w,
                          const int* __restrict__ idx,
                          u16* __restrict__ wA, u16* __restrict__ w1,
                          u16* __restrict__ w2,
                          const u16* __restrict__ x,
                          const float* __restrict__ g_base,
                          const float* __restrict__ b_base,
                          u16* __restrict__ abf) {
  __shared__ float sh[32 * 33];
  int b = blockIdx.x, tid = threadIdx.x;
  if (b < 4096) {
    int kk = b >> 11;              // 0 or 1
    int c = b & 2047;
    int id = idx[kk];
    float (*tile)[33] = (float(*)[33])sh;
    const float* src; u16* dst; int K, N, n0, k0;
    if (c < 1024) {
      K = 1024; N = 1024; src = aw + (size_t)id * 1024 * 1024;
      n0 = (c & 31) * 32; k0 = (c >> 5) * 32;
      dst = wA + (size_t)kk * 1024 * 1024;
    } else if (c < 1536) {
      int cc = c - 1024; K = 1024; N = 512;
      src = f1w + (size_t)id * 1024 * 512;
      n0 = (cc & 15) * 32; k0 = (cc >> 4) * 32;
      dst = w1 + (size_t)kk * 512 * 1024;
    } else {
      int cc = c - 1536; K = 512; N = 1024;
      src = f2w + (size_t)id * 512 * 1024;
      n0 = (cc & 31) * 32; k0 = (cc >> 5) * 32;
      dst = w2 + (size_t)kk * 512 * 1024;
    }
    int tx = tid & 31, ty = tid >> 5;
#pragma unroll
    for (int j = 0; j < 4; ++j) {
      int kr = k0 + ty + j * 8;
      tile[ty + j * 8][tx] = src[(size_t)kr * N + n0 + tx];
    }
    __syncthreads();
#pragma unroll
    for (int j = 0; j < 4; ++j) {
      int nr = n0 + ty + j * 8;
      dst[(size_t)nr * K + k0 + tx] = f2bf(tile[tx][ty + j * 8]);
    }
    return;
  }
  // ---- LN1 (k=0) ----
  int row = b - 4096, t = tid;
  int id = idx[0];
  const float* g = g_base + (size_t)id * HDIM;
  const float* bb = b_base + (size_t)id * HDIM;
  u16x4_t xv = ((const u16x4_t*)(x + (size_t)row * HDIM))[t];
  float v0 = b2f(xv.x), v1 = b2f(xv.y), v2 = b2f(xv.z), v3 = b2f(xv.w);
  float s = v0 + v1 + v2 + v3;
  float q = v0 * v0 + v1 * v1 + v2 * v2 + v3 * v3;
  for (int o = 32; o; o >>= 1) { s += __shfl_down(s, o); q += __shfl_down(q, o); }
  float* ss = sh; float* sq = sh + 8;
  int wave = t >> 6, lane = t & 63;
  if (lane == 0) { ss[wave] = s; sq[wave] = q; }
  __syncthreads();
  if (t == 0) {
    float S = ss[0] + ss[1] + ss[2] + ss[3];
    float Q = sq[0] + sq[1] + sq[2] + sq[3];
    ss[0] = S * (1.0f / 1024.0f);
    sq[0] = Q * (1.0f / 1024.0f);
  }
  __syncthreads();
  float mean = ss[0];
  float var = sq[0] - mean * mean;
  float rs = rsqrtf(var + 1e-5f);
  float4 gv = ((const float4*)g)[t];
  float4 bv = ((const float4*)bb)[t];
  u16x4_t o4;
  o4.x = f2bf((v0 - mean) * rs * gv.x + bv.x);
  o4.y = f2bf((v1 - mean) * rs * gv.y + bv.y);
  o4.z = f2bf((v2 - mean) * rs * gv.z + bv.z);
  o4.w = f2bf((v3 - mean) * rs * gv.w + bv.w);
  ((u16x4_t*)(abf + (size_t)row * HDIM))[t] = o4;
}

// --------------------------- layernorm -> bf16 ------------------------------
__global__ void ln_kernel(const u16* __restrict__ x,
                          const float* __restrict__ g_base,
                          const float* __restrict__ b_base,
                          const int* __restrict__ idx_ptr, int slot,
                          u16* __restrict__ out) {
  int row = blockIdx.x, t = threadIdx.x;     // 256 threads, 4 elems each
  size_t off = (size_t)idx_ptr[slot] * HDIM;
  const float* g = g_base + off;
  const float* b = b_base + off;
  u16x4_t xv = ((const u16x4_t*)(x + (size_t)row * HDIM))[t];
  float v0 = b2f(xv.x), v1 = b2f(xv.y), v2 = b2f(xv.z), v3 = b2f(xv.w);
  float s = v0 + v1 + v2 + v3;
  float q = v0 * v0 + v1 * v1 + v2 * v2 + v3 * v3;
  for (int o = 32; o; o >>= 1) { s += __shfl_down(s, o); q += __shfl_down(q, o); }
  __shared__ float ss[4], sq[4];
  int wave = t >> 6, lane = t & 63;
  if (lane == 0) { ss[wave] = s; sq[wave] = q; }
  __syncthreads();
  if (t == 0) {
    float S = ss[0] + ss[1] + ss[2] + ss[3];
    float Q = sq[0] + sq[1] + sq[2] + sq[3];
    ss[0] = S * (1.0f / 1024.0f);
    sq[0] = Q * (1.0f / 1024.0f);
  }
  __syncthreads();
  float mean = ss[0];
  float var = sq[0] - mean * mean;
  float rs = rsqrtf(var + 1e-5f);
  float4 gv = ((const float4*)g)[t];
  float4 bv = ((const float4*)b)[t];
  u16x4_t o4;
  o4.x = f2bf((v0 - mean) * rs * gv.x + bv.x);
  o4.y = f2bf((v1 - mean) * rs * gv.y + bv.y);
  o4.z = f2bf((v2 - mean) * rs * gv.z + bv.z);
  o4.w = f2bf((v3 - mean) * rs * gv.w + bv.w);
  ((u16x4_t*)(out + (size_t)row * HDIM))[t] = o4;
}

// --------------------------- layer GEMM (BK=128) ----------------------------
// C[M=4096][N] = A[M][K](bf16) * Bt[N][K](bf16)^T, fp32 acc, fused epilogues.
// BK=128, 256 threads = 4 waves (2Mx2N), 16B-group XOR swizzle. Row-major
// epilogue. Residual x is bf16 (fp32 math in-register).
// EPI 0: x = bf16(x + 0.5*(c+bias)*scale)       (attn; N==H)
// EPI 1: outb = bf16(gelu(c+bias))              (ff1)
// EPI 2: x = bf16((x + 0.5*(c+bias)) * lscale)  (ff2)
template <int BM, int BN, int EPI>
__global__ __launch_bounds__(256) void gemm_layer(
    const u16* __restrict__ A, const u16* __restrict__ Bt, int N, int K,
    const float* __restrict__ bias_base, const int* __restrict__ idx_ptr,
    int slot, int bias_stride, const float* __restrict__ scale,
    u16* __restrict__ xres, u16* __restrict__ outb, float lscale) {
  constexpr int TM = BM / 2, TN = BN / 2;
  constexpr int FM = TM / 16, FN = TN / 16;
  constexpr int NLD = (BM + BN) / 16;       // gloads/thread/step (BK=128)
  __shared__ __align__(16) u16 lds[(BM + BN) * 128];

  const int tid = threadIdx.x, wave = tid >> 6, lane = tid & 63;
  const int m0 = blockIdx.y * BM, n0 = blockIdx.x * BN;
  const int wm = wave >> 1, wn = wave & 1;
  const int fr = lane & 15, g = lane >> 4;
  const float* bias =
      bias_base + (idx_ptr ? (size_t)idx_ptr[slot] * bias_stride : 0);

  const u16* gbase[NLD];
  unsigned ldsoff[NLD];
#pragma unroll
  for (int j = 0; j < NLD; ++j) {
    int lo = (tid + j * 256) * 16;        // byte offset in (BM+BN)*256 tile
    int q = (lo >> 4) & 15;               // 16B-group within 256B row
    if (lo < BM * 256) {
      int row = lo >> 8;
      gbase[j] = A + (size_t)(m0 + row) * K + (q ^ (row & 7)) * 8;
    } else {
      int bo = lo - BM * 256;
      int row = bo >> 8;
      gbase[j] = Bt + (size_t)(n0 + row) * K + (q ^ (row & 7)) * 8;
    }
    ldsoff[j] = (unsigned)(lo >> 1);
  }

  unsigned offA[FM][4], offB[FN][4];
#pragma unroll
  for (int mi = 0; mi < FM; ++mi)
#pragma unroll
    for (int kk = 0; kk < 4; ++kk)
      offA[mi][kk] = (unsigned)((wm * TM + mi * 16 + fr) * 256 +
                                (((kk * 4 + g) ^ (fr & 7)) << 4));
#pragma unroll
  for (int ni = 0; ni < FN; ++ni)
#pragma unroll
    for (int kk = 0; kk < 4; ++kk)
      offB[ni][kk] = (unsigned)(BM * 256 + (wn * TN + ni * 16 + fr) * 256 +
                                (((kk * 4 + g) ^ (fr & 7)) << 4));

  f32x4 acc[FM][FN];
#pragma unroll
  for (int i = 0; i < FM; ++i)
#pragma unroll
    for (int j = 0; j < FN; ++j) acc[i][j] = (f32x4){0.f, 0.f, 0.f, 0.f};

  for (int kt = 0; kt < K; kt += 128) {
#pragma unroll
    for (int j = 0; j < NLD; ++j) gload16(gbase[j] + kt, lds + ldsoff[j]);
    __syncthreads();
#pragma unroll
    for (int kk = 0; kk < 4; ++kk) {
      bf16x8 af[FM], bf[FN];
#pragma unroll
      for (int mi = 0; mi < FM; ++mi)
        af[mi] = *(const bf16x8*)((const char*)lds + offA[mi][kk]);
#pragma unroll
      for (int ni = 0; ni < FN; ++ni)
        bf[ni] = *(const bf16x8*)((const char*)lds + offB[ni][kk]);
#pragma unroll
      for (int mi = 0; mi < FM; ++mi)
#pragma unroll
        for (int ni = 0; ni < FN; ++ni)
          acc[mi][ni] = __builtin_amdgcn_mfma_f32_16x16x32_bf16(
              af[mi], bf[ni], acc[mi][ni], 0, 0, 0);
    }
    __syncthreads();
  }

  // ---- epilogue: row-major order, ni innermost ----
  const int rb = g * 4, cn = fr;
  float bvv[FN], svv[FN];
#pragma unroll
  for (int ni = 0; ni < FN; ++ni) {
    int n = n0 + wn * TN + ni * 16 + cn;
    bvv[ni] = bias[n];
    svv[ni] = (EPI == 0) ? scale[n] : 0.f;
  }
#pragma unroll
  for (int mi = 0; mi < FM; ++mi) {
#pragma unroll
    for (int r = 0; r < 4; ++r) {
      int m = m0 + wm * TM + mi * 16 + rb + r;
      size_t base = (size_t)m * N + n0 + wn * TN + cn;
#pragma unroll
      for (int ni = 0; ni < FN; ++ni) {
        float c = acc[mi][ni][r] + bvv[ni];
        size_t o = base + ni * 16;
        if (EPI == 0) {
          float xv = b2f(xres[o]);
          xres[o] = f2bf(xv + 0.5f * (c * svv[ni]));
        } else if (EPI == 1) {
          float ge = 0.5f * c * (1.0f + erff(c * 0.70710678118654752f));
          outb[o] = f2bf(ge);
        } else {
          float xv = b2f(xres[o]);
          xres[o] = f2bf((xv + 0.5f * c) * lscale);
        }
      }
    }
  }
}

// --------------------------- LM-head GEMM (round-12 best) -------------------
// out[4096][32000] = x[4096][1024](bf16) @ lmT[32000][1024](bf16)^T + bias.
// 256x256 tile, 8 waves 2Mx4N. BK=64, double-buffered, 4 phases; units
// aligned to phase reads; VMW(2)+BARR at P1/P2 only. Swizzle, XCD chunking,
// row-major NT epilogue. Closed at measured plateau (~318 us, 7 variants).
__global__ __launch_bounds__(512, 2) void gemm_lm(
    const u16* __restrict__ A, const u16* __restrict__ Bt,
    const float* __restrict__ bias, float* __restrict__ out) {
  constexpr int K = HDIM;      // 1024
  constexpr int N = VOC;       // 32000
  constexpr int NT = K / 64;   // 16 K-tiles
  __shared__ __align__(16) u16 smbuf[2 * 32768];   // 2 x 64 KB

  const int tid = threadIdx.x, wid = tid >> 6, lane = tid & 63;
  const int bid = blockIdx.x;
  const int vbid = (bid & 7) * 250 + (bid >> 3);
  const int n0 = (vbid >> 4) * 256;
  const int m0 = (vbid & 15) * 256;
  const int wm = wid >> 2, wn = wid & 3;   // 2 x 4 waves
  const int fr = lane & 15, g = lane >> 4;

  const int r0 = tid >> 3, q = tid & 7;
  const int sg = (q ^ (r0 & 7)) * 8;         // u16 offset of swizzled group
  const u16* usrc[4][2];
  unsigned uoff[4][2];                       // u16 offsets within a buffer
  usrc[0][0] = Bt + (size_t)(n0 + r0) * K + sg;        uoff[0][0] = 16384u + tid * 8;
  usrc[0][1] = Bt + (size_t)(n0 + 64 + r0) * K + sg;   uoff[0][1] = 20480u + tid * 8;
  usrc[1][0] = Bt + (size_t)(n0 + 128 + r0) * K + sg;  uoff[1][0] = 24576u + tid * 8;
  usrc[1][1] = Bt + (size_t)(n0 + 192 + r0) * K + sg;  uoff[1][1] = 28672u + tid * 8;
  usrc[2][0] = A + (size_t)(m0 + r0) * K + sg;         uoff[2][0] = 0u + tid * 8;
  usrc[2][1] = A + (size_t)(m0 + 128 + r0) * K + sg;   uoff[2][1] = 8192u + tid * 8;
  usrc[3][0] = A + (size_t)(m0 + 64 + r0) * K + sg;    uoff[3][0] = 4096u + tid * 8;
  usrc[3][1] = A + (size_t)(m0 + 192 + r0) * K + sg;   uoff[3][1] = 12288u + tid * 8;

  unsigned offA[8][2], offB[4][2];
#pragma unroll
  for (int mi = 0; mi < 8; ++mi)
#pragma unroll
    for (int kk = 0; kk < 2; ++kk)
      offA[mi][kk] = (unsigned)((wm * 128 + mi * 16 + fr) * 128 +
                                (((kk * 4 + g) ^ (fr & 7)) << 4));
#pragma unroll
  for (int ni = 0; ni < 4; ++ni)
#pragma unroll
    for (int kk = 0; kk < 2; ++kk)
      offB[ni][kk] = (unsigned)(32768 + (wn * 64 + ni * 16 + fr) * 128 +
                                (((kk * 4 + g) ^ (fr & 7)) << 4));

  f32x4 acc[8][4];
#pragma unroll
  for (int i = 0; i < 8; ++i)
#pragma unroll
    for (int j = 0; j < 4; ++j) acc[i][j] = (f32x4){0.f, 0.f, 0.f, 0.f};

  // prologue: stage tile 0 into buf0 in ledger order u0,u1,u2,u3
#pragma unroll
  for (int u = 0; u < 4; ++u) {
    gload16(usrc[u][0], smbuf + uoff[u][0]);
    gload16(usrc[u][1], smbuf + uoff[u][1]);
  }

  for (int t = 0; t < NT; ++t) {
    const char* cb = (const char*)smbuf + (size_t)(t & 1) * 65536;
    u16* nb = smbuf + ((t + 1) & 1) * 32768;
    const int ko = (t + 1) * 64;
    const bool st = (t + 1 < NT);
    bf16x8 avl[4], avh[4], bv[4];
    // ---- P1: kk0, mi0-3 ---- needs u0,u1,u2 of tile t (VMW(2) leaves u3)
    VMW(2);
    BARR();
#pragma unroll
    for (int ni = 0; ni < 4; ++ni) bv[ni] = *(const bf16x8*)(cb + offB[ni][0]);
#pragma unroll
    for (int mi = 0; mi < 4; ++mi) avl[mi] = *(const bf16x8*)(cb + offA[mi][0]);
    if (st) {
      gload16(usrc[0][0] + ko, nb + uoff[0][0]);
      gload16(usrc[0][1] + ko, nb + uoff[0][1]);
    }
    __builtin_amdgcn_s_setprio(1);
#pragma unroll
    for (int mi = 0; mi < 4; ++mi)
#pragma unroll
      for (int ni = 0; ni < 4; ++ni)
        acc[mi][ni] = __builtin_amdgcn_mfma_f32_16x16x32_bf16(
            avl[mi], bv[ni], acc[mi][ni], 0, 0, 0);
    __builtin_amdgcn_s_setprio(0);
    // ---- P2: kk0, mi4-7 ---- needs u3 of tile t
    if (t < NT - 1) { VMW(2); } else { VMW(0); }
    BARR();
#pragma unroll
    for (int mi = 0; mi < 4; ++mi)
      avh[mi] = *(const bf16x8*)(cb + offA[4 + mi][0]);
    if (st) {
      gload16(usrc[1][0] + ko, nb + uoff[1][0]);
      gload16(usrc[1][1] + ko, nb + uoff[1][1]);
    }
    __builtin_amdgcn_s_setprio(1);
#pragma unroll
    for (int mi = 0; mi < 4; ++mi)
#pragma unroll
      for (int ni = 0; ni < 4; ++ni)
        acc[4 + mi][ni] = __builtin_amdgcn_mfma_f32_16x16x32_bf16(
            avh[mi], bv[ni], acc[4 + mi][ni], 0, 0, 0);
    __builtin_amdgcn_s_setprio(0);
    // ---- P3: kk1, mi0-3 ---- (resident)
#pragma unroll
    for (int ni = 0; ni < 4; ++ni) bv[ni] = *(const bf16x8*)(cb + offB[ni][1]);
#pragma unroll
    for (int mi = 0; mi < 4; ++mi) avl[mi] = *(const bf16x8*)(cb + offA[mi][1]);
    if (st) {
      gload16(usrc[2][0] + ko, nb + uoff[2][0]);
      gload16(usrc[2][1] + ko, nb + uoff[2][1]);
    }
    __builtin_amdgcn_s_setprio(1);
#pragma unroll
    for (int mi = 0; mi < 4; ++mi)
#pragma unroll
      for (int ni = 0; ni < 4; ++ni)
        acc[mi][ni] = __builtin_amdgcn_mfma_f32_16x16x32_bf16(
            avl[mi], bv[ni], acc[mi][ni], 0, 0, 0);
    __builtin_amdgcn_s_setprio(0);
    // ---- P4: kk1, mi4-7 ----
#pragma unroll
    for (int mi = 0; mi < 4; ++mi)
      avh[mi] = *(const bf16x8*)(cb + offA[4 + mi][1]);
    if (st) {
      gload16(usrc[3][0] + ko, nb + uoff[3][0]);
      gload16(usrc[3][1] + ko, nb + uoff[3][1]);
    }
    __builtin_amdgcn_s_setprio(1);
#pragma unroll
    for (int mi = 0; mi < 4; ++mi)
#pragma unroll
      for (int ni = 0; ni < 4; ++ni)
        acc[4 + mi][ni] = __builtin_amdgcn_mfma_f32_16x16x32_bf16(
            avh[mi], bv[ni], acc[4 + mi][ni], 0, 0, 0);
    __builtin_amdgcn_s_setprio(0);
  }

  // ---- epilogue: row-major, ni innermost -> 4 consecutive 64B chunks ------
  const int rb = g * 4, cn = fr;
  float bvv[4];
#pragma unroll
  for (int ni = 0; ni < 4; ++ni) bvv[ni] = bias[n0 + wn * 64 + ni * 16 + cn];
#pragma unroll
  for (int mi = 0; mi < 8; ++mi) {
#pragma unroll
    for (int r = 0; r < 4; ++r) {
      int m = m0 + wm * 128 + mi * 16 + rb + r;
      float* orow = out + (size_t)m * N + n0 + wn * 64 + cn;
#pragma unroll
      for (int ni = 0; ni < 4; ++ni)
        __builtin_nontemporal_store(acc[mi][ni][r] + bvv[ni], orow + ni * 16);
    }
  }
}

// --------------------------- launch ----------------------------------------
extern "C" void kernel_launch(void* const* d_in, const int* in_sizes, int n_in,
                              void* d_out, int out_size, void* d_ws,
                              size_t ws_size, hipStream_t stream) {
  (void)in_sizes; (void)n_in; (void)out_size; (void)ws_size;
  const int*   ids    = (const int*)d_in[0];
  const float* emb    = (const float*)d_in[1];
  const float* pos    = (const float*)d_in[2];
  const float* tf     = (const float*)d_in[3];
  const float* lm_w   = (const float*)d_in[4];
  const float* lm_b   = (const float*)d_in[5];
  const float* sel_w  = (const float*)d_in[6];
  const float* sel_b  = (const float*)d_in[7];
  const float* g1     = (const float*)d_in[8];
  const float* b1     = (const float*)d_in[9];
  const float* attn_w = (const float*)d_in[10];
  const float* attn_b = (const float*)d_in[11];
  const float* g2     = (const float*)d_in[12];
  const float* b2     = (const float*)d_in[13];
  const float* ff1_w  = (const float*)d_in[14];
  const float* ff1_b  = (const float*)d_in[15];
  const float* ff2_w  = (const float*)d_in[16];
  const float* ff2_b  = (const float*)d_in[17];
  const float* tg     = (const float*)d_in[18];
  float* out = (float*)d_out;

  char* ws = (char*)d_ws;
  u16*   x       = (u16*)(ws + 0);            // 8 MB bf16 residual
  u16*   wA      = (u16*)(ws + 8388608);      // 4 MB: attn W^T, k=0/1
  u16*   w1      = (u16*)(ws + 12582912);     // 2 MB: ff1 W^T, k=0/1
  u16*   w2      = (u16*)(ws + 14680064);     // 2 MB: ff2 W^T, k=0/1
  u16*   abf     = (u16*)(ws + 16777216);     // 8 MB bf16 LN out
  u16*   tbuf    = (u16*)(ws + 25165824);     // 4 MB bf16 gelu out
  u16*   lmT     = (u16*)(ws + 33554432);     // 62.5 MB lm W^T
  float* partial = (float*)(ws + 99090432);   // 256 KB router colsum
  float* scalev  = (float*)(ws + 99352576);   // 8 KB torsion scales
  int*   idx     = (int*)(ws + 99360768);     // 8 B top-2 indices

  embed_lm_kernel<<<MTOT + VOC, 256, 0, stream>>>(ids, emb, pos, x, lm_w, lmT);

  for (int l = 0; l < NLAYER; ++l) {
    colsum_kernel<<<64, 256, 0, stream>>>(x, partial);
    router_finalize<<<1, 1024, 0, stream>>>(
        partial, sel_w + (size_t)l * HDIM * NBLK, sel_b + l * NBLK,
        tg + (size_t)l * NBLK * HDIM, tf, idx, scalev);
    const float* aw_l  = attn_w + (size_t)l * NBLK * HDIM * HDIM;
    const float* f1w_l = ff1_w + (size_t)l * NBLK * HDIM * HFF;
    const float* f2w_l = ff2_w + (size_t)l * NBLK * HFF * HDIM;
    for (int k = 0; k < 2; ++k) {
      if (k == 0) {
        // both experts' transposes + LN1(k=0) in one launch
        prep_both<<<8192, 256, 0, stream>>>(
            aw_l, f1w_l, f2w_l, idx, wA, w1, w2, x,
            g1 + (size_t)l * NBLK * HDIM, b1 + (size_t)l * NBLK * HDIM, abf);
      } else {
        // weights already transposed; only LN1(k=1)
        ln_kernel<<<MTOT, 256, 0, stream>>>(x, g1 + (size_t)l * NBLK * HDIM,
                                            b1 + (size_t)l * NBLK * HDIM, idx,
                                            1, abf);
      }
      const u16* wAk = wA + (size_t)k * 1024 * 1024;
      const u16* w1k = w1 + (size_t)k * 512 * 1024;
      const u16* w2k = w2 + (size_t)k * 512 * 1024;
      // attn: 64x64 tile, grid (16, 64) = 1024 blocks = 4 blocks/CU
      gemm_layer<64, 64, 0><<<dim3(16, 64), 256, 0, stream>>>(
          abf, wAk, HDIM, HDIM, attn_b + (size_t)l * NBLK * HDIM, idx, k, HDIM,
          scalev + k * HDIM, x, nullptr, 1.0f);
      ln_kernel<<<MTOT, 256, 0, stream>>>(x, g2 + (size_t)l * NBLK * HDIM,
                                          b2 + (size_t)l * NBLK * HDIM, idx, k,
                                          abf);
      // ff1: 64x64 tile, grid (8, 64) = 512 blocks
      gemm_layer<64, 64, 1><<<dim3(8, 64), 256, 0, stream>>>(
          abf, w1k, HFF, HDIM, ff1_b + (size_t)l * NBLK * HFF, idx, k, HFF,
          nullptr, nullptr, tbuf, 1.0f);
      float lsc = (k == 1) ? 1.5f : 1.0f;
      // ff2: 64x64 tile, grid (16, 64) = 1024 blocks = 4 blocks/CU
      gemm_layer<64, 64, 2><<<dim3(16, 64), 256, 0, stream>>>(
          tbuf, w2k, HDIM, HFF, ff2_b + (size_t)l * NBLK * HDIM, idx, k, HDIM,
          nullptr, x, nullptr, lsc);
    }
  }

  gemm_lm<<<2000, 512, 0, stream>>>(x, lmT, lm_b, out);
}